// Round 5
// baseline (554.905 us; speedup 1.0000x reference)
//
#include <hip/hip_runtime.h>
#include <hip/hip_bf16.h>

#define D128 128

typedef __attribute__((ext_vector_type(8))) short bf16x8;
typedef __attribute__((ext_vector_type(4))) float f32x4;

__device__ __forceinline__ float b2f(unsigned short u) {
    union { unsigned int i; float f; } z;
    z.i = ((unsigned int)u) << 16;
    return z.f;
}

__device__ __forceinline__ unsigned short f2b(float f) {
    union { float f; unsigned int i; } z;
    z.f = f;
    unsigned int r = z.i + 0x7FFFu + ((z.i >> 16) & 1u);  // round-to-nearest-even
    return (unsigned short)(r >> 16);
}

__device__ __forceinline__ f32x4 mfma16(bf16x8 a, bf16x8 b, f32x4 c) {
    return __builtin_amdgcn_mfma_f32_16x16x32_bf16(a, b, c, 0, 0, 0);
}

#define CHUNK 8192
#define MAXBINS 512
#define BINCAP 8192
#define XBB 1536

// ---------------------------------------------------------------------------
// Prep 1 (3-way block partition):
//   blocks [0,64)        : compose Wc = Wg @ W1 (fp32), bc = Wg @ b1
//   blocks [64,64+B)     : per-chunk dst histogram -> M[bin*B + chunk]
//   blocks [64+B, ...)   : xb = bf16(leaky(x, 0.01))  (streaming)
// ---------------------------------------------------------------------------
__global__ __launch_bounds__(256) void k_prep1(
    const float* __restrict__ x,
    const float* __restrict__ W1, const float* __restrict__ Wg,
    const float* __restrict__ b1,
    const int* __restrict__ ei, int* __restrict__ M,
    float* __restrict__ Wc, float* __restrict__ bc,
    unsigned short* __restrict__ xb,
    int N, int E, int B, int nbins)
{
    __shared__ float wgr[256];
    __shared__ int hist[MAXBINS];
    const int t = threadIdx.x;
    if (blockIdx.x < 64) {
        const int i0 = blockIdx.x * 2;
        wgr[t] = Wg[i0 * 128 + t];          // rows i0, i0+1 contiguous
        __syncthreads();
        const int half = t >> 7;
        const int j = t & 127;
        const float* wr = &wgr[half * 128];
        float acc = 0.f;
        #pragma unroll 4
        for (int k = 0; k < 128; ++k)
            acc += wr[k] * W1[k * 128 + j];
        Wc[(i0 + half) * 128 + j] = acc;
        if (j == 0) {
            float ab = 0.f;
            for (int k = 0; k < 128; ++k) ab += wr[k] * b1[k];
            bc[i0 + half] = ab;
        }
    } else if (blockIdx.x < 64 + B) {
        const int chunk = blockIdx.x - 64;
        for (int i = t; i < nbins; i += 256) hist[i] = 0;
        __syncthreads();
        const int base = chunk * CHUNK;
        const int end = min(base + CHUNK, E);
        for (int e = base + t; e < end; e += 256)
            atomicAdd(&hist[ei[E + e] >> 8], 1);
        __syncthreads();
        for (int i = t; i < nbins; i += 256)
            M[i * B + chunk] = hist[i];
    } else {
        const size_t total = (size_t)N * 128;
        const size_t stride = (size_t)XBB * 256 * 8;
        for (size_t i = ((size_t)(blockIdx.x - 64 - B) * 256 + t) * 8; i + 8 <= total; i += stride) {
            float4 f0 = *(const float4*)(x + i);
            float4 f1 = *(const float4*)(x + i + 4);
            float v[8] = { f0.x, f0.y, f0.z, f0.w, f1.x, f1.y, f1.z, f1.w };
            union { uint4 q; unsigned short s[8]; } o;
            #pragma unroll
            for (int jj = 0; jj < 8; ++jj) {
                float f = v[jj];
                f = f >= 0.f ? f : 0.01f * f;
                o.s[jj] = f2b(f);
            }
            *(uint4*)(xb + i) = o.q;
        }
    }
}

// ---------------------------------------------------------------------------
// Prep 2 + scan1 merged:
//   blocks 0..8   : Wcat fragment-major build (rows 128..143 = att-folded)
//   blocks 9..16  : W2l fragment-major build
//   block  17     : lbias
//   blocks 18..   : scan of M (1024 elems per block, 256 threads x 4)
// ---------------------------------------------------------------------------
__global__ __launch_bounds__(256) void k_prep2s(
    const float* __restrict__ Wc, const float* __restrict__ bc,
    const float* __restrict__ att_s, const float* __restrict__ att_d,
    const float* __restrict__ W2,
    unsigned short* __restrict__ Wcat, unsigned short* __restrict__ W2l,
    float* __restrict__ lbias,
    const int* __restrict__ M, int* __restrict__ scanned,
    int* __restrict__ bsum, int nM)
{
    __shared__ int lds[256];
    const int b = blockIdx.x, t = threadIdx.x;
    if (b < 9) {
        const int q = b * 256 + t;           // 0..2303
        const int ct = q >> 8, rem = q & 255;
        const int ks = rem >> 6, lane = rem & 63;
        const int ldiv = lane >> 4, lmod = lane & 15;
        const int kb = ks * 32 + ldiv * 8;
        float v[8];
        if (ct < 8) {
            const int rho = ct * 16 + lmod;
            const float4 a = *(const float4*)(Wc + rho * 128 + kb);
            const float4 bq = *(const float4*)(Wc + rho * 128 + kb + 4);
            v[0] = a.x; v[1] = a.y; v[2] = a.z; v[3] = a.w;
            v[4] = bq.x; v[5] = bq.y; v[6] = bq.z; v[7] = bq.w;
        } else {
            #pragma unroll
            for (int e = 0; e < 8; ++e) v[e] = 0.f;
            if (lmod < 8) {
                const int hh = lmod & 3;
                const float* av = lmod < 4 ? att_s : att_d;
                for (int c = 0; c < 32; ++c) {
                    const float w = av[hh * 32 + c];
                    const float* wrow = Wc + (hh * 32 + c) * 128 + kb;
                    #pragma unroll
                    for (int e = 0; e < 8; ++e) v[e] += w * wrow[e];
                }
            }
        }
        union { uint4 qq; unsigned short s[8]; } o;
        #pragma unroll
        for (int e = 0; e < 8; ++e) o.s[e] = f2b(v[e]);
        *(uint4*)(Wcat + q * 8) = o.qq;
    } else if (b < 17) {
        const int q = (b - 9) * 256 + t;     // 0..2047
        const int ct = q >> 8, rem = q & 255;
        const int ks = rem >> 6, lane = rem & 63;
        const int ldiv = lane >> 4, lmod = lane & 15;
        const int kb = ks * 32 + ldiv * 8;
        const int rho = ct * 16 + lmod;
        const float4 a = *(const float4*)(W2 + rho * 128 + kb);
        const float4 bq = *(const float4*)(W2 + rho * 128 + kb + 4);
        union { uint4 qq; unsigned short s[8]; } o;
        o.s[0] = f2b(a.x); o.s[1] = f2b(a.y); o.s[2] = f2b(a.z); o.s[3] = f2b(a.w);
        o.s[4] = f2b(bq.x); o.s[5] = f2b(bq.y); o.s[6] = f2b(bq.z); o.s[7] = f2b(bq.w);
        *(uint4*)(W2l + q * 8) = o.qq;
    } else if (b == 17) {
        if (t < 144) {
            float v = 0.f;
            if (t < 128) v = bc[t];
            else if (t < 136) {
                const int hh = (t - 128) & 3;
                const float* av = t < 132 ? att_s : att_d;
                for (int c = 0; c < 32; ++c) v += av[hh * 32 + c] * bc[hh * 32 + c];
            }
            lbias[t] = v;
        }
    } else {
        // scan block: 1024 elements, exclusive within block
        const int sid = b - 18;
        const int g0 = sid * 1024 + t * 4;
        int v0 = g0     < nM ? M[g0]     : 0;
        int v1 = g0 + 1 < nM ? M[g0 + 1] : 0;
        int v2 = g0 + 2 < nM ? M[g0 + 2] : 0;
        int v3 = g0 + 3 < nM ? M[g0 + 3] : 0;
        const int s = v0 + v1 + v2 + v3;
        lds[t] = s;
        __syncthreads();
        #pragma unroll
        for (int off = 1; off < 256; off <<= 1) {
            int tv = t >= off ? lds[t - off] : 0;
            __syncthreads();
            lds[t] += tv;
            __syncthreads();
        }
        int run = lds[t] - s;   // exclusive
        if (g0     < nM) scanned[g0]     = run;
        run += v0;
        if (g0 + 1 < nM) scanned[g0 + 1] = run;
        run += v1;
        if (g0 + 2 < nM) scanned[g0 + 2] = run;
        run += v2;
        if (g0 + 3 < nM) scanned[g0 + 3] = run;
        if (t == 255) bsum[sid] = lds[255];
    }
}

// ---------------------------------------------------------------------------
// GEMM (h + logits) merged with kA2 scatter (independent block ranges).
//   blocks [0, nbg)     : h = xb @ Wcat^T -> hsplit (plane-major) + asrc/adst
//   blocks [nbg, nbg+B) : scatter (src,dst) into bin regions
// ---------------------------------------------------------------------------
__global__ __launch_bounds__(256) void k_gemmA2(
    const unsigned short* __restrict__ xb,
    const unsigned short* __restrict__ Wcat,
    const float* __restrict__ lbias,
    unsigned short* __restrict__ hsplit,
    float* __restrict__ asrc, float* __restrict__ adst,
    const int* __restrict__ ei, const int* __restrict__ scanned,
    const int* __restrict__ bsum, int2* __restrict__ binned,
    int N, int E, int B, int nbins, int nM, int nbg)
{
    __shared__ __align__(16) unsigned char smem[36864];
    const int t = threadIdx.x;
    if (blockIdx.x < nbg) {
        unsigned short* sW = (unsigned short*)smem;
        const int wave = t >> 6, lane = t & 63, lmod = lane & 15, ldiv = lane >> 4;
        const int rowBase = blockIdx.x * 64;
        const size_t N16 = (size_t)N * 16;

        uint4 w[9];
        #pragma unroll
        for (int r = 0; r < 9; ++r)
            w[r] = *(const uint4*)(Wcat + r * 2048 + t * 8);

        int row = rowBase + wave * 16 + lmod;
        row = min(row, N - 1);
        bf16x8 afr[4];
        #pragma unroll
        for (int ks = 0; ks < 4; ++ks)
            afr[ks] = *(const bf16x8*)(xb + (size_t)row * D128 + ks * 32 + ldiv * 8);

        #pragma unroll
        for (int r = 0; r < 9; ++r)
            *(uint4*)&sW[r * 2048 + t * 8] = w[r];
        __syncthreads();

        f32x4 acc[9] = {};
        #pragma unroll
        for (int ct = 0; ct < 9; ++ct) {
            #pragma unroll
            for (int ks = 0; ks < 4; ++ks) {
                bf16x8 bfr = *(const bf16x8*)&sW[(ct * 256 + ks * 64 + lane) * 8];
                acc[ct] = mfma16(afr[ks], bfr, acc[ct]);
            }
        }

        const int orow = rowBase + wave * 16 + ldiv * 4;
        #pragma unroll
        for (int ct = 0; ct < 8; ++ct) {
            const float bias = lbias[ct * 16 + lmod];
            #pragma unroll
            for (int r = 0; r < 4; ++r)
                if (orow + r < N)
                    hsplit[(size_t)ct * N16 + (size_t)(orow + r) * 16 + lmod] =
                        f2b(acc[ct][r] + bias);
        }
        if (lmod < 8) {
            const float lb = lbias[128 + lmod];
            float* dst = lmod < 4 ? asrc : adst;
            const int hh = lmod & 3;
            #pragma unroll
            for (int r = 0; r < 4; ++r)
                if (orow + r < N)
                    dst[(size_t)(orow + r) * 4 + hh] = acc[8][r] + lb;
        }
    } else {
        int* cursor = (int*)smem;                      // MAXBINS ints
        int* bpre   = (int*)(smem + MAXBINS * 4);      // 1024 ints
        const int chunk = blockIdx.x - nbg;
        const int nsb = (nM + 1023) >> 10;
        for (int i = t; i < nsb; i += 256) bpre[i] = bsum[i];
        __syncthreads();
        if (t == 0) {
            int run = 0;
            for (int i = 0; i < nsb; ++i) { int tv = bpre[i]; bpre[i] = run; run += tv; }
        }
        __syncthreads();
        for (int i = t; i < nbins; i += 256) {
            const int idx = i * B + chunk;
            cursor[i] = scanned[idx] + bpre[idx >> 10];
        }
        __syncthreads();
        const int base = chunk * CHUNK;
        const int end = min(base + CHUNK, E);
        for (int e = base + t; e < end; e += 256) {
            const int s = ei[e], d = ei[E + e];
            const int pos = atomicAdd(&cursor[d >> 8], 1);   // LDS atomic (fast)
            binned[pos] = make_int2(s, d);
        }
    }
}

// ---------------------------------------------------------------------------
// kB: per-bin local CSR in LDS -> bucket + rowstart/rowend, then per-dst
// softmax weights: wexp[h][pos] = exp(leaky(asrc+adst)), denom[d][h].
// ---------------------------------------------------------------------------
__global__ __launch_bounds__(256) void kB(
    const int2* __restrict__ binned, const int* __restrict__ scanned,
    const int* __restrict__ bsum,
    const float* __restrict__ asrc, const float* __restrict__ adst,
    int* __restrict__ bucket,
    int* __restrict__ rowstart, int* __restrict__ rowend,
    float* __restrict__ wexp, float* __restrict__ denom,
    int E, int B, int nbins, int N, int nM)
{
    __shared__ int2 eb[BINCAP];       // 64 KB
    __shared__ int ldeg[256];
    __shared__ int lscan[256];
    __shared__ int lcur[256];
    __shared__ int bpre[1024];
    const int nsb = (nM + 1023) >> 10;
    for (int i = threadIdx.x; i < nsb; i += 256) bpre[i] = bsum[i];
    __syncthreads();
    if (threadIdx.x == 0) {
        int run = 0;
        for (int i = 0; i < nsb; ++i) { int tv = bpre[i]; bpre[i] = run; run += tv; }
    }
    __syncthreads();
    const int bin = blockIdx.x;
    const int i0 = bin * B;
    const int binstart = scanned[i0] + bpre[i0 >> 10];
    int binend;
    if (bin + 1 < nbins) {
        const int i1 = (bin + 1) * B;
        binend = scanned[i1] + bpre[i1 >> 10];
    } else {
        binend = E;
    }
    int n = binend - binstart;
    if (n > BINCAP) n = BINCAP;   // statistically impossible; safety clamp

    for (int i = threadIdx.x; i < n; i += 256) eb[i] = binned[binstart + i];
    ldeg[threadIdx.x] = 0;
    __syncthreads();
    for (int i = threadIdx.x; i < n; i += 256)
        atomicAdd(&ldeg[eb[i].y & 255], 1);
    __syncthreads();
    const int v = ldeg[threadIdx.x];
    lscan[threadIdx.x] = v;
    __syncthreads();
    #pragma unroll
    for (int off = 1; off < 256; off <<= 1) {
        int tv = threadIdx.x >= off ? lscan[threadIdx.x - off] : 0;
        __syncthreads();
        lscan[threadIdx.x] += tv;
        __syncthreads();
    }
    const int excl = lscan[threadIdx.x] - v;
    lcur[threadIdx.x] = excl;
    const int d = (bin << 8) + threadIdx.x;
    if (d < N) {
        rowstart[d] = binstart + excl;
        rowend[d]   = binstart + excl + v;
    }
    __syncthreads();
    for (int i = threadIdx.x; i < n; i += 256) {
        const int lp = atomicAdd(&lcur[eb[i].y & 255], 1);  // LDS atomic
        bucket[binstart + lp] = eb[i].x;
    }
    __syncthreads();
    // per-dst softmax weights (rows now final in global bucket; L2-hot)
    if (d < N && v > 0) {
        const float4 adv = *(const float4*)(adst + (size_t)d * 4);
        const float ad0 = adv.x, ad1 = adv.y, ad2 = adv.z, ad3 = adv.w;
        float dn0 = 0.f, dn1 = 0.f, dn2 = 0.f, dn3 = 0.f;
        const int rs = binstart + excl;
        for (int i = 0; i < v; ++i) {
            const int s = bucket[rs + i];
            const float4 as = *(const float4*)(asrc + (size_t)s * 4);
            float a0 = as.x + ad0; a0 = a0 >= 0.f ? a0 : 0.2f * a0;
            float a1 = as.y + ad1; a1 = a1 >= 0.f ? a1 : 0.2f * a1;
            float a2 = as.z + ad2; a2 = a2 >= 0.f ? a2 : 0.2f * a2;
            float a3 = as.w + ad3; a3 = a3 >= 0.f ? a3 : 0.2f * a3;
            const float w0 = __expf(a0), w1 = __expf(a1);
            const float w2 = __expf(a2), w3 = __expf(a3);
            wexp[rs + i]                   = w0;
            wexp[(size_t)E + rs + i]       = w1;
            wexp[(size_t)2 * E + rs + i]   = w2;
            wexp[(size_t)3 * E + rs + i]   = w3;
            dn0 += w0; dn1 += w1; dn2 += w2; dn3 += w3;
        }
        *(float4*)(denom + (size_t)d * 4) = make_float4(dn0, dn1, dn2, dn3);
    } else if (d < N) {
        *(float4*)(denom + (size_t)d * 4) = make_float4(0.f, 0.f, 0.f, 0.f);
    }
}

// ---------------------------------------------------------------------------
// Channel-split aggregation: 8 passes (pass-major blocks). Pass p handles
// plane p = 16 channels of head p>>1. Per-pass gather table = 3.2 MB
// (fits per-XCD L2). 2 lanes per dst, 128 dsts per block.
// Epilogue: /denom + bias_g + leaky -> outsplit (plane-major bf16).
// ---------------------------------------------------------------------------
__global__ __launch_bounds__(256) void k_pass(
    const int* __restrict__ bucket,
    const int* __restrict__ rowstart, const int* __restrict__ rowend,
    const float* __restrict__ wexp, const float* __restrict__ denom,
    const unsigned short* __restrict__ hsplit,
    const float* __restrict__ bias_g,
    unsigned short* __restrict__ outsplit,
    int N, int E, int nbd)
{
    const int pass = blockIdx.x / nbd;
    const int bb   = blockIdx.x - pass * nbd;
    const int head = pass >> 1;
    const int t = threadIdx.x;
    const int grp = t >> 1;           // dst within block (0..127)
    const int l   = t & 1;            // channel-half lane (8 ch, 16 B)
    const int d = bb * 128 + grp;
    if (d >= N) return;

    const size_t N16 = (size_t)N * 16;
    const int start = rowstart[d];
    const int end   = rowend[d];
    const float* wp = wexp + (size_t)head * E;
    const unsigned short* hp = hsplit + (size_t)pass * N16 + (l << 3);

    float acc[8] = {0.f, 0.f, 0.f, 0.f, 0.f, 0.f, 0.f, 0.f};
    int j = start;
    for (; j + 2 <= end; j += 2) {
        const int s0 = bucket[j];
        const int s1 = bucket[j + 1];
        const float w0 = wp[j];
        const float w1 = wp[j + 1];
        const uint4 h0 = *(const uint4*)(hp + ((size_t)s0 << 4));
        const uint4 h1 = *(const uint4*)(hp + ((size_t)s1 << 4));
        acc[0] += w0 * b2f((unsigned short)(h0.x & 0xFFFFu)) + w1 * b2f((unsigned short)(h1.x & 0xFFFFu));
        acc[1] += w0 * b2f((unsigned short)(h0.x >> 16))     + w1 * b2f((unsigned short)(h1.x >> 16));
        acc[2] += w0 * b2f((unsigned short)(h0.y & 0xFFFFu)) + w1 * b2f((unsigned short)(h1.y & 0xFFFFu));
        acc[3] += w0 * b2f((unsigned short)(h0.y >> 16))     + w1 * b2f((unsigned short)(h1.y >> 16));
        acc[4] += w0 * b2f((unsigned short)(h0.z & 0xFFFFu)) + w1 * b2f((unsigned short)(h1.z & 0xFFFFu));
        acc[5] += w0 * b2f((unsigned short)(h0.z >> 16))     + w1 * b2f((unsigned short)(h1.z >> 16));
        acc[6] += w0 * b2f((unsigned short)(h0.w & 0xFFFFu)) + w1 * b2f((unsigned short)(h1.w & 0xFFFFu));
        acc[7] += w0 * b2f((unsigned short)(h0.w >> 16))     + w1 * b2f((unsigned short)(h1.w >> 16));
    }
    if (j < end) {
        const int s0 = bucket[j];
        const float w0 = wp[j];
        const uint4 h0 = *(const uint4*)(hp + ((size_t)s0 << 4));
        acc[0] += w0 * b2f((unsigned short)(h0.x & 0xFFFFu));
        acc[1] += w0 * b2f((unsigned short)(h0.x >> 16));
        acc[2] += w0 * b2f((unsigned short)(h0.y & 0xFFFFu));
        acc[3] += w0 * b2f((unsigned short)(h0.y >> 16));
        acc[4] += w0 * b2f((unsigned short)(h0.z & 0xFFFFu));
        acc[5] += w0 * b2f((unsigned short)(h0.z >> 16));
        acc[6] += w0 * b2f((unsigned short)(h0.w & 0xFFFFu));
        acc[7] += w0 * b2f((unsigned short)(h0.w >> 16));
    }

    const float inv = 1.f / (denom[(size_t)d * 4 + head] + 1e-16f);
    const int chb = pass * 16 + l * 8;
    const float4 bg0 = *(const float4*)(bias_g + chb);
    const float4 bg1 = *(const float4*)(bias_g + chb + 4);
    const float bg[8] = { bg0.x, bg0.y, bg0.z, bg0.w, bg1.x, bg1.y, bg1.z, bg1.w };
    unsigned short s8[8];
    #pragma unroll
    for (int k = 0; k < 8; ++k) {
        float vv = acc[k] * inv + bg[k];
        vv = vv >= 0.f ? vv : 0.01f * vv;
        s8[k] = f2b(vv);
    }
    uint4 o;
    o.x = ((unsigned int)s8[1] << 16) | s8[0];
    o.y = ((unsigned int)s8[3] << 16) | s8[2];
    o.z = ((unsigned int)s8[5] << 16) | s8[4];
    o.w = ((unsigned int)s8[7] << 16) | s8[6];
    *(uint4*)(outsplit + (size_t)pass * N16 + (size_t)d * 16 + l * 8) = o;
}

// ---------------------------------------------------------------------------
// Final GEMM: out = A @ W2^T + b2, A read plane-major (bias+leaky baked).
// ---------------------------------------------------------------------------
__global__ __launch_bounds__(256) void k_final(
    const unsigned short* __restrict__ outsplit,
    const unsigned short* __restrict__ W2l,
    const float* __restrict__ b2,
    float* __restrict__ out, int N)
{
    __shared__ __align__(16) unsigned short sW[16384];   // 32768 B
    const int t = threadIdx.x;
    const int wave = t >> 6, lane = t & 63, lmod = lane & 15, ldiv = lane >> 4;
    const int rowBase = blockIdx.x * 64;
    const size_t N16 = (size_t)N * 16;

    uint4 w[8];
    #pragma unroll
    for (int r = 0; r < 8; ++r)
        w[r] = *(const uint4*)(W2l + r * 2048 + t * 8);

    int row = rowBase + wave * 16 + lmod;
    row = min(row, N - 1);
    bf16x8 afr[4];
    #pragma unroll
    for (int ks = 0; ks < 4; ++ks) {
        const int plane = 2 * ks + (ldiv >> 1);
        const int cho = (ldiv & 1) * 8;
        afr[ks] = *(const bf16x8*)(outsplit + (size_t)plane * N16 + (size_t)row * 16 + cho);
    }

    #pragma unroll
    for (int r = 0; r < 8; ++r)
        *(uint4*)&sW[r * 2048 + t * 8] = w[r];
    __syncthreads();

    f32x4 acc[8] = {};
    #pragma unroll
    for (int ct = 0; ct < 8; ++ct) {
        #pragma unroll
        for (int ks = 0; ks < 4; ++ks) {
            bf16x8 bfr = *(const bf16x8*)&sW[(ct * 256 + ks * 64 + lane) * 8];
            acc[ct] = mfma16(afr[ks], bfr, acc[ct]);
        }
    }

    const int orow = rowBase + wave * 16 + ldiv * 4;
    #pragma unroll
    for (int ct = 0; ct < 8; ++ct) {
        const int col = ct * 16 + lmod;
        const float bb = b2[col];
        #pragma unroll
        for (int r = 0; r < 4; ++r)
            if (orow + r < N)
                out[(size_t)(orow + r) * D128 + col] = acc[ct][r] + bb;
    }
}

// ---------------------------------------------------------------------------
extern "C" void kernel_launch(void* const* d_in, const int* in_sizes, int n_in,
                              void* d_out, int out_size, void* d_ws, size_t ws_size,
                              hipStream_t stream)
{
    const float* x    = (const float*)d_in[0];
    const int*   ei   = (const int*)d_in[1];
    // d_in[2] edge_type: unused by forward
    const float* W1   = (const float*)d_in[3];
    const float* b1   = (const float*)d_in[4];
    const float* Wg   = (const float*)d_in[5];
    const float* atts = (const float*)d_in[6];
    const float* attd = (const float*)d_in[7];
    const float* bg   = (const float*)d_in[8];
    const float* W2   = (const float*)d_in[9];
    const float* b2   = (const float*)d_in[10];
    float* out = (float*)d_out;

    const int N = in_sizes[0] / D128;
    const int E = in_sizes[1] / 2;

    const int B     = (E + CHUNK - 1) / CHUNK;       // edge chunks
    const int nbins = (N + 255) >> 8;                // coarse bins
    const int nM    = nbins * B;
    const int nsb   = (nM + 1023) / 1024;

    // workspace layout (16B aligned pieces)
    char* ws = (char*)d_ws;
    float* Wc = (float*)ws;                                    // 64 KB
    size_t off = 65536;
    float* bc    = (float*)(ws + off); off += 512;
    float* lbias = (float*)(ws + off); off += 1024;
    unsigned short* Wcat = (unsigned short*)(ws + off); off += 36864;
    unsigned short* W2l  = (unsigned short*)(ws + off); off += 32768;
    unsigned short* xb   = (unsigned short*)(ws + off); off += (size_t)N * D128 * 2;
    float* wexp = (float*)xb;   // alias: xb dead after k_gemmA2; 4*E*4 == N*128*2 sized region
    unsigned short* hsplit = (unsigned short*)(ws + off); off += (size_t)N * D128 * 2;
    float* asrc = (float*)(ws + off); off += (size_t)N * 4 * 4;
    float* adst = (float*)(ws + off); off += (size_t)N * 4 * 4;
    float* denom = (float*)(ws + off); off += (size_t)N * 4 * 4;
    int* M       = (int*)(ws + off); off += (size_t)nM * 4;
    int* scanned = (int*)(ws + off); off += (size_t)nM * 4;
    int* bsum    = (int*)(ws + off); off += 1024 * 4;
    int2* binned = (int2*)(ws + off); off += (size_t)E * 8;
    int* bucket  = (int*)(ws + off); off += (size_t)E * 4;
    int* rowstart = (int*)(ws + off); off += (size_t)N * 4;
    int* rowend   = (int*)(ws + off); off += (size_t)N * 4;
    unsigned short* outsplit = (unsigned short*)(ws + off); off += (size_t)N * D128 * 2;
    // safety: wexp needs 4*E*4 bytes <= N*128*2  (1.6M*16 = 25.6MB == 100K*256)

    // 1) compose Wc + dst histogram + bf16(leaky(x))
    k_prep1<<<64 + B + XBB, 256, 0, stream>>>(x, W1, Wg, b1, ei, M, Wc, bc, xb,
                                              N, E, B, nbins);
    // 2) fragment-major weights + scan of M
    k_prep2s<<<18 + nsb, 256, 0, stream>>>(Wc, bc, atts, attd, W2, Wcat, W2l,
                                           lbias, M, scanned, bsum, nM);
    // 3) h/logits GEMM (plane-major h) + edge scatter into bins
    const int nbg = (N + 63) / 64;
    k_gemmA2<<<nbg + B, 256, 0, stream>>>(xb, Wcat, lbias, hsplit, asrc, adst,
                                          ei, scanned, bsum, binned,
                                          N, E, B, nbins, nM, nbg);
    // 4) bin-local CSR + softmax weights/denominators
    kB<<<nbins, 256, 0, stream>>>(binned, scanned, bsum, asrc, adst, bucket,
                                  rowstart, rowend, wexp, denom,
                                  E, B, nbins, N, nM);
    // 5) channel-split aggregation (8 passes, L2-resident gather tables)
    const int nbd = (N + 127) / 128;
    k_pass<<<8 * nbd, 256, 0, stream>>>(bucket, rowstart, rowend, wexp, denom,
                                        hsplit, bg, outsplit, N, E, nbd);
    // 6) final GEMM
    k_final<<<nbg, 256, 0, stream>>>(outsplit, W2l, b2, out, N);
}

// Round 6
// 320.435 us; speedup vs baseline: 1.7317x; 1.7317x over previous
//
#include <hip/hip_runtime.h>
#include <hip/hip_bf16.h>

#define D128 128

typedef __attribute__((ext_vector_type(8))) short bf16x8;
typedef __attribute__((ext_vector_type(4))) float f32x4;

__device__ __forceinline__ float b2f(unsigned short u) {
    union { unsigned int i; float f; } z;
    z.i = ((unsigned int)u) << 16;
    return z.f;
}

__device__ __forceinline__ unsigned short f2b(float f) {
    union { float f; unsigned int i; } z;
    z.f = f;
    unsigned int r = z.i + 0x7FFFu + ((z.i >> 16) & 1u);  // round-to-nearest-even
    return (unsigned short)(r >> 16);
}

__device__ __forceinline__ f32x4 mfma16(bf16x8 a, bf16x8 b, f32x4 c) {
    return __builtin_amdgcn_mfma_f32_16x16x32_bf16(a, b, c, 0, 0, 0);
}

#define CHUNK 8192
#define MAXBINS 512
#define BINCAP 8192
#define XBB 1536

// ---------------------------------------------------------------------------
// Prep 1 (3-way block partition):
//   blocks [0,64)        : compose Wc = Wg @ W1 (fp32), bc = Wg @ b1
//   blocks [64,64+B)     : per-chunk dst histogram -> M[bin*B + chunk]
//   blocks [64+B, ...)   : xb = bf16(leaky(x, 0.01))  (streaming)
// ---------------------------------------------------------------------------
__global__ __launch_bounds__(256) void k_prep1(
    const float* __restrict__ x,
    const float* __restrict__ W1, const float* __restrict__ Wg,
    const float* __restrict__ b1,
    const int* __restrict__ ei, int* __restrict__ M,
    float* __restrict__ Wc, float* __restrict__ bc,
    unsigned short* __restrict__ xb,
    int N, int E, int B, int nbins)
{
    __shared__ float wgr[256];
    __shared__ int hist[MAXBINS];
    const int t = threadIdx.x;
    if (blockIdx.x < 64) {
        const int i0 = blockIdx.x * 2;
        wgr[t] = Wg[i0 * 128 + t];          // rows i0, i0+1 contiguous
        __syncthreads();
        const int half = t >> 7;
        const int j = t & 127;
        const float* wr = &wgr[half * 128];
        float acc = 0.f;
        #pragma unroll 4
        for (int k = 0; k < 128; ++k)
            acc += wr[k] * W1[k * 128 + j];
        Wc[(i0 + half) * 128 + j] = acc;
        if (j == 0) {
            float ab = 0.f;
            for (int k = 0; k < 128; ++k) ab += wr[k] * b1[k];
            bc[i0 + half] = ab;
        }
    } else if (blockIdx.x < 64 + B) {
        const int chunk = blockIdx.x - 64;
        for (int i = t; i < nbins; i += 256) hist[i] = 0;
        __syncthreads();
        const int base = chunk * CHUNK;
        const int end = min(base + CHUNK, E);
        for (int e = base + t; e < end; e += 256)
            atomicAdd(&hist[ei[E + e] >> 8], 1);
        __syncthreads();
        for (int i = t; i < nbins; i += 256)
            M[i * B + chunk] = hist[i];
    } else {
        const size_t total = (size_t)N * 128;
        const size_t stride = (size_t)XBB * 256 * 8;
        for (size_t i = ((size_t)(blockIdx.x - 64 - B) * 256 + t) * 8; i + 8 <= total; i += stride) {
            float4 f0 = *(const float4*)(x + i);
            float4 f1 = *(const float4*)(x + i + 4);
            float v[8] = { f0.x, f0.y, f0.z, f0.w, f1.x, f1.y, f1.z, f1.w };
            union { uint4 q; unsigned short s[8]; } o;
            #pragma unroll
            for (int jj = 0; jj < 8; ++jj) {
                float f = v[jj];
                f = f >= 0.f ? f : 0.01f * f;
                o.s[jj] = f2b(f);
            }
            *(uint4*)(xb + i) = o.q;
        }
    }
}

// ---------------------------------------------------------------------------
// Prep 2 + scan1 merged:
//   blocks 0..8   : Wcat fragment-major build (rows 128..143 = att-folded)
//   blocks 9..16  : W2l fragment-major build
//   block  17     : lbias
//   blocks 18..   : scan of M (1024 elems per block, 256 threads x 4)
// ---------------------------------------------------------------------------
__global__ __launch_bounds__(256) void k_prep2s(
    const float* __restrict__ Wc, const float* __restrict__ bc,
    const float* __restrict__ att_s, const float* __restrict__ att_d,
    const float* __restrict__ W2,
    unsigned short* __restrict__ Wcat, unsigned short* __restrict__ W2l,
    float* __restrict__ lbias,
    const int* __restrict__ M, int* __restrict__ scanned,
    int* __restrict__ bsum, int nM)
{
    __shared__ int lds[256];
    const int b = blockIdx.x, t = threadIdx.x;
    if (b < 9) {
        const int q = b * 256 + t;           // 0..2303
        const int ct = q >> 8, rem = q & 255;
        const int ks = rem >> 6, lane = rem & 63;
        const int ldiv = lane >> 4, lmod = lane & 15;
        const int kb = ks * 32 + ldiv * 8;
        float v[8];
        if (ct < 8) {
            const int rho = ct * 16 + lmod;
            const float4 a = *(const float4*)(Wc + rho * 128 + kb);
            const float4 bq = *(const float4*)(Wc + rho * 128 + kb + 4);
            v[0] = a.x; v[1] = a.y; v[2] = a.z; v[3] = a.w;
            v[4] = bq.x; v[5] = bq.y; v[6] = bq.z; v[7] = bq.w;
        } else {
            #pragma unroll
            for (int e = 0; e < 8; ++e) v[e] = 0.f;
            if (lmod < 8) {
                const int hh = lmod & 3;
                const float* av = lmod < 4 ? att_s : att_d;
                for (int c = 0; c < 32; ++c) {
                    const float w = av[hh * 32 + c];
                    const float* wrow = Wc + (hh * 32 + c) * 128 + kb;
                    #pragma unroll
                    for (int e = 0; e < 8; ++e) v[e] += w * wrow[e];
                }
            }
        }
        union { uint4 qq; unsigned short s[8]; } o;
        #pragma unroll
        for (int e = 0; e < 8; ++e) o.s[e] = f2b(v[e]);
        *(uint4*)(Wcat + q * 8) = o.qq;
    } else if (b < 17) {
        const int q = (b - 9) * 256 + t;     // 0..2047
        const int ct = q >> 8, rem = q & 255;
        const int ks = rem >> 6, lane = rem & 63;
        const int ldiv = lane >> 4, lmod = lane & 15;
        const int kb = ks * 32 + ldiv * 8;
        const int rho = ct * 16 + lmod;
        const float4 a = *(const float4*)(W2 + rho * 128 + kb);
        const float4 bq = *(const float4*)(W2 + rho * 128 + kb + 4);
        union { uint4 qq; unsigned short s[8]; } o;
        o.s[0] = f2b(a.x); o.s[1] = f2b(a.y); o.s[2] = f2b(a.z); o.s[3] = f2b(a.w);
        o.s[4] = f2b(bq.x); o.s[5] = f2b(bq.y); o.s[6] = f2b(bq.z); o.s[7] = f2b(bq.w);
        *(uint4*)(W2l + q * 8) = o.qq;
    } else if (b == 17) {
        if (t < 144) {
            float v = 0.f;
            if (t < 128) v = bc[t];
            else if (t < 136) {
                const int hh = (t - 128) & 3;
                const float* av = t < 132 ? att_s : att_d;
                for (int c = 0; c < 32; ++c) v += av[hh * 32 + c] * bc[hh * 32 + c];
            }
            lbias[t] = v;
        }
    } else {
        // scan block: 1024 elements, exclusive within block
        const int sid = b - 18;
        const int g0 = sid * 1024 + t * 4;
        int v0 = g0     < nM ? M[g0]     : 0;
        int v1 = g0 + 1 < nM ? M[g0 + 1] : 0;
        int v2 = g0 + 2 < nM ? M[g0 + 2] : 0;
        int v3 = g0 + 3 < nM ? M[g0 + 3] : 0;
        const int s = v0 + v1 + v2 + v3;
        lds[t] = s;
        __syncthreads();
        #pragma unroll
        for (int off = 1; off < 256; off <<= 1) {
            int tv = t >= off ? lds[t - off] : 0;
            __syncthreads();
            lds[t] += tv;
            __syncthreads();
        }
        int run = lds[t] - s;   // exclusive
        if (g0     < nM) scanned[g0]     = run;
        run += v0;
        if (g0 + 1 < nM) scanned[g0 + 1] = run;
        run += v1;
        if (g0 + 2 < nM) scanned[g0 + 2] = run;
        run += v2;
        if (g0 + 3 < nM) scanned[g0 + 3] = run;
        if (t == 255) bsum[sid] = lds[255];
    }
}

// ---------------------------------------------------------------------------
// GEMM (h + logits) merged with edge scatter (independent block ranges).
//   blocks [0, nbg)     : h = xb @ Wcat^T -> hfeat (row-major) + asrc/adst
//   blocks [nbg, nbg+B) : scatter (src,dst) into bin regions
// ---------------------------------------------------------------------------
__global__ __launch_bounds__(256) void k_gemmA2(
    const unsigned short* __restrict__ xb,
    const unsigned short* __restrict__ Wcat,
    const float* __restrict__ lbias,
    unsigned short* __restrict__ hfeat,
    float* __restrict__ asrc, float* __restrict__ adst,
    const int* __restrict__ ei, const int* __restrict__ scanned,
    const int* __restrict__ bsum, int2* __restrict__ binned,
    int N, int E, int B, int nbins, int nM, int nbg)
{
    __shared__ __align__(16) unsigned char smem[36864];
    const int t = threadIdx.x;
    if (blockIdx.x < nbg) {
        unsigned short* sW = (unsigned short*)smem;
        const int wave = t >> 6, lane = t & 63, lmod = lane & 15, ldiv = lane >> 4;
        const int rowBase = blockIdx.x * 64;

        uint4 w[9];
        #pragma unroll
        for (int r = 0; r < 9; ++r)
            w[r] = *(const uint4*)(Wcat + r * 2048 + t * 8);

        int row = rowBase + wave * 16 + lmod;
        row = min(row, N - 1);
        bf16x8 afr[4];
        #pragma unroll
        for (int ks = 0; ks < 4; ++ks)
            afr[ks] = *(const bf16x8*)(xb + (size_t)row * D128 + ks * 32 + ldiv * 8);

        #pragma unroll
        for (int r = 0; r < 9; ++r)
            *(uint4*)&sW[r * 2048 + t * 8] = w[r];
        __syncthreads();

        f32x4 acc[9] = {};
        #pragma unroll
        for (int ct = 0; ct < 9; ++ct) {
            #pragma unroll
            for (int ks = 0; ks < 4; ++ks) {
                bf16x8 bfr = *(const bf16x8*)&sW[(ct * 256 + ks * 64 + lane) * 8];
                acc[ct] = mfma16(afr[ks], bfr, acc[ct]);
            }
        }

        const int orow = rowBase + wave * 16 + ldiv * 4;
        #pragma unroll
        for (int ct = 0; ct < 8; ++ct) {
            const int col = ct * 16 + lmod;
            const float bias = lbias[col];
            #pragma unroll
            for (int r = 0; r < 4; ++r)
                if (orow + r < N)
                    hfeat[(size_t)(orow + r) * D128 + col] = f2b(acc[ct][r] + bias);
        }
        if (lmod < 8) {
            const float lb = lbias[128 + lmod];
            float* dst = lmod < 4 ? asrc : adst;
            const int hh = lmod & 3;
            #pragma unroll
            for (int r = 0; r < 4; ++r)
                if (orow + r < N)
                    dst[(size_t)(orow + r) * 4 + hh] = acc[8][r] + lb;
        }
    } else {
        int* cursor = (int*)smem;                      // MAXBINS ints
        int* bpre   = (int*)(smem + MAXBINS * 4);      // 1024 ints
        const int chunk = blockIdx.x - nbg;
        const int nsb = (nM + 1023) >> 10;
        for (int i = t; i < nsb; i += 256) bpre[i] = bsum[i];
        __syncthreads();
        if (t == 0) {
            int run = 0;
            for (int i = 0; i < nsb; ++i) { int tv = bpre[i]; bpre[i] = run; run += tv; }
        }
        __syncthreads();
        for (int i = t; i < nbins; i += 256) {
            const int idx = i * B + chunk;
            cursor[i] = scanned[idx] + bpre[idx >> 10];
        }
        __syncthreads();
        const int base = chunk * CHUNK;
        const int end = min(base + CHUNK, E);
        for (int e = base + t; e < end; e += 256) {
            const int s = ei[e], d = ei[E + e];
            const int pos = atomicAdd(&cursor[d >> 8], 1);   // LDS atomic (fast)
            binned[pos] = make_int2(s, d);
        }
    }
}

// ---------------------------------------------------------------------------
// kB: per-bin local CSR in LDS -> bucket + rowstart/rowend. Local bsum prefix.
// ---------------------------------------------------------------------------
__global__ __launch_bounds__(256) void kB(
    const int2* __restrict__ binned, const int* __restrict__ scanned,
    const int* __restrict__ bsum, int* __restrict__ bucket,
    int* __restrict__ rowstart, int* __restrict__ rowend,
    int E, int B, int nbins, int N, int nM)
{
    __shared__ int2 eb[BINCAP];       // 64 KB
    __shared__ int ldeg[256];
    __shared__ int lscan[256];
    __shared__ int lcur[256];
    __shared__ int bpre[1024];
    const int nsb = (nM + 1023) >> 10;
    for (int i = threadIdx.x; i < nsb; i += 256) bpre[i] = bsum[i];
    __syncthreads();
    if (threadIdx.x == 0) {
        int run = 0;
        for (int i = 0; i < nsb; ++i) { int tv = bpre[i]; bpre[i] = run; run += tv; }
    }
    __syncthreads();
    const int bin = blockIdx.x;
    const int i0 = bin * B;
    const int binstart = scanned[i0] + bpre[i0 >> 10];
    int binend;
    if (bin + 1 < nbins) {
        const int i1 = (bin + 1) * B;
        binend = scanned[i1] + bpre[i1 >> 10];
    } else {
        binend = E;
    }
    int n = binend - binstart;
    if (n > BINCAP) n = BINCAP;   // statistically impossible; safety clamp

    for (int i = threadIdx.x; i < n; i += 256) eb[i] = binned[binstart + i];
    ldeg[threadIdx.x] = 0;
    __syncthreads();
    for (int i = threadIdx.x; i < n; i += 256)
        atomicAdd(&ldeg[eb[i].y & 255], 1);
    __syncthreads();
    const int v = ldeg[threadIdx.x];
    lscan[threadIdx.x] = v;
    __syncthreads();
    #pragma unroll
    for (int off = 1; off < 256; off <<= 1) {
        int tv = threadIdx.x >= off ? lscan[threadIdx.x - off] : 0;
        __syncthreads();
        lscan[threadIdx.x] += tv;
        __syncthreads();
    }
    const int excl = lscan[threadIdx.x] - v;
    lcur[threadIdx.x] = excl;
    const int d = (bin << 8) + threadIdx.x;
    if (d < N) {
        rowstart[d] = binstart + excl;
        rowend[d]   = binstart + excl + v;
    }
    __syncthreads();
    for (int i = threadIdx.x; i < n; i += 256) {
        const int lp = atomicAdd(&lcur[eb[i].y & 255], 1);  // LDS atomic
        bucket[binstart + lp] = eb[i].x;
    }
}

// ---------------------------------------------------------------------------
// GAT aggregation, 16 lanes per dst, depth-2 (best measured). Epilogue bakes
// +bias_g and leaky(0.01) so k_final's A-operand is load-only bf16.
// bucket stream loaded nontemporal (keep L2 for hfeat).
// ---------------------------------------------------------------------------
__global__ __launch_bounds__(256) void k_gat(
    const int* __restrict__ bucket,
    const int* __restrict__ rowstart, const int* __restrict__ rowend,
    const float* __restrict__ asrc, const float* __restrict__ adst,
    const unsigned short* __restrict__ hfeat,
    const float* __restrict__ bias_g,
    unsigned short* __restrict__ outbf, int N)
{
    const int wave = threadIdx.x >> 6;
    const int lane = threadIdx.x & 63;
    const int g    = lane >> 4;          // dst-group within wave (0..3)
    const int gl   = lane & 15;          // lane within group
    const int h    = gl >> 2;            // head 0..3
    const int d    = blockIdx.x * 16 + wave * 4 + g;

    int start = 0, end = 0;
    float a_d = 0.f;
    if (d < N) {
        start = rowstart[d];
        end   = rowend[d];
        a_d   = adst[(size_t)d * 4 + h];
    }
    const unsigned int chb = (unsigned int)(gl << 3);   // channel offset (elems)
    const unsigned short* hbase = hfeat + chb;

    float acc[8] = {0.f, 0.f, 0.f, 0.f, 0.f, 0.f, 0.f, 0.f};
    float denom = 0.f;

    int j = start;
    for (; j + 2 <= end; j += 2) {
        const int s0 = __builtin_nontemporal_load(bucket + j);
        const int s1 = __builtin_nontemporal_load(bucket + j + 1);
        const float as0 = asrc[((size_t)s0 << 2) + h];
        const float as1 = asrc[((size_t)s1 << 2) + h];
        const uint4 hp0 = *(const uint4*)(hbase + ((unsigned int)s0 << 7));
        const uint4 hp1 = *(const uint4*)(hbase + ((unsigned int)s1 << 7));
        float a0 = as0 + a_d; a0 = a0 >= 0.f ? a0 : 0.2f * a0;
        float a1 = as1 + a_d; a1 = a1 >= 0.f ? a1 : 0.2f * a1;
        const float w0 = __expf(a0), w1 = __expf(a1);
        denom += w0 + w1;
        acc[0] += w0 * b2f((unsigned short)(hp0.x & 0xFFFFu)) + w1 * b2f((unsigned short)(hp1.x & 0xFFFFu));
        acc[1] += w0 * b2f((unsigned short)(hp0.x >> 16))     + w1 * b2f((unsigned short)(hp1.x >> 16));
        acc[2] += w0 * b2f((unsigned short)(hp0.y & 0xFFFFu)) + w1 * b2f((unsigned short)(hp1.y & 0xFFFFu));
        acc[3] += w0 * b2f((unsigned short)(hp0.y >> 16))     + w1 * b2f((unsigned short)(hp1.y >> 16));
        acc[4] += w0 * b2f((unsigned short)(hp0.z & 0xFFFFu)) + w1 * b2f((unsigned short)(hp1.z & 0xFFFFu));
        acc[5] += w0 * b2f((unsigned short)(hp0.z >> 16))     + w1 * b2f((unsigned short)(hp1.z >> 16));
        acc[6] += w0 * b2f((unsigned short)(hp0.w & 0xFFFFu)) + w1 * b2f((unsigned short)(hp1.w & 0xFFFFu));
        acc[7] += w0 * b2f((unsigned short)(hp0.w >> 16))     + w1 * b2f((unsigned short)(hp1.w >> 16));
    }
    if (j < end) {
        const int s0 = __builtin_nontemporal_load(bucket + j);
        const float as0 = asrc[((size_t)s0 << 2) + h];
        const uint4 hp0 = *(const uint4*)(hbase + ((unsigned int)s0 << 7));
        float a0 = as0 + a_d; a0 = a0 >= 0.f ? a0 : 0.2f * a0;
        const float w0 = __expf(a0);
        denom += w0;
        acc[0] += w0 * b2f((unsigned short)(hp0.x & 0xFFFFu));
        acc[1] += w0 * b2f((unsigned short)(hp0.x >> 16));
        acc[2] += w0 * b2f((unsigned short)(hp0.y & 0xFFFFu));
        acc[3] += w0 * b2f((unsigned short)(hp0.y >> 16));
        acc[4] += w0 * b2f((unsigned short)(hp0.z & 0xFFFFu));
        acc[5] += w0 * b2f((unsigned short)(hp0.z >> 16));
        acc[6] += w0 * b2f((unsigned short)(hp0.w & 0xFFFFu));
        acc[7] += w0 * b2f((unsigned short)(hp0.w >> 16));
    }

    if (d < N) {
        const float inv = 1.f / (denom + 1e-16f);
        const float4 bg0 = *(const float4*)(bias_g + chb);
        const float4 bg1 = *(const float4*)(bias_g + chb + 4);
        const float bg[8] = { bg0.x, bg0.y, bg0.z, bg0.w, bg1.x, bg1.y, bg1.z, bg1.w };
        unsigned short s[8];
        #pragma unroll
        for (int k2 = 0; k2 < 8; ++k2) {
            float v = acc[k2] * inv + bg[k2];
            v = v >= 0.f ? v : 0.01f * v;
            s[k2] = f2b(v);
        }
        uint4 o;
        o.x = ((unsigned int)s[1] << 16) | s[0];
        o.y = ((unsigned int)s[3] << 16) | s[2];
        o.z = ((unsigned int)s[5] << 16) | s[4];
        o.w = ((unsigned int)s[7] << 16) | s[6];
        *(uint4*)(outbf + (((unsigned int)d << 7) + chb)) = o;
    }
}

// ---------------------------------------------------------------------------
// Final GEMM: out = outbf @ W2^T + b2  (A already has bias+leaky baked in)
// ---------------------------------------------------------------------------
__global__ __launch_bounds__(256) void k_final(
    const unsigned short* __restrict__ gatbf,
    const unsigned short* __restrict__ W2l,
    const float* __restrict__ b2,
    float* __restrict__ out, int N)
{
    __shared__ __align__(16) unsigned short sW[16384];   // 32768 B
    const int t = threadIdx.x;
    const int wave = t >> 6, lane = t & 63, lmod = lane & 15, ldiv = lane >> 4;
    const int rowBase = blockIdx.x * 64;

    uint4 w[8];
    #pragma unroll
    for (int r = 0; r < 8; ++r)
        w[r] = *(const uint4*)(W2l + r * 2048 + t * 8);

    int row = rowBase + wave * 16 + lmod;
    row = min(row, N - 1);
    bf16x8 afr[4];
    #pragma unroll
    for (int ks = 0; ks < 4; ++ks)
        afr[ks] = *(const bf16x8*)(gatbf + (size_t)row * D128 + ks * 32 + ldiv * 8);

    #pragma unroll
    for (int r = 0; r < 8; ++r)
        *(uint4*)&sW[r * 2048 + t * 8] = w[r];
    __syncthreads();

    f32x4 acc[8] = {};
    #pragma unroll
    for (int ct = 0; ct < 8; ++ct) {
        #pragma unroll
        for (int ks = 0; ks < 4; ++ks) {
            bf16x8 bfr = *(const bf16x8*)&sW[(ct * 256 + ks * 64 + lane) * 8];
            acc[ct] = mfma16(afr[ks], bfr, acc[ct]);
        }
    }

    const int orow = rowBase + wave * 16 + ldiv * 4;
    #pragma unroll
    for (int ct = 0; ct < 8; ++ct) {
        const int col = ct * 16 + lmod;
        const float bb = b2[col];
        #pragma unroll
        for (int r = 0; r < 4; ++r)
            if (orow + r < N)
                out[(size_t)(orow + r) * D128 + col] = acc[ct][r] + bb;
    }
}

// ---------------------------------------------------------------------------
extern "C" void kernel_launch(void* const* d_in, const int* in_sizes, int n_in,
                              void* d_out, int out_size, void* d_ws, size_t ws_size,
                              hipStream_t stream)
{
    const float* x    = (const float*)d_in[0];
    const int*   ei   = (const int*)d_in[1];
    // d_in[2] edge_type: unused by forward
    const float* W1   = (const float*)d_in[3];
    const float* b1   = (const float*)d_in[4];
    const float* Wg   = (const float*)d_in[5];
    const float* atts = (const float*)d_in[6];
    const float* attd = (const float*)d_in[7];
    const float* bg   = (const float*)d_in[8];
    const float* W2   = (const float*)d_in[9];
    const float* b2   = (const float*)d_in[10];
    float* out = (float*)d_out;

    const int N = in_sizes[0] / D128;
    const int E = in_sizes[1] / 2;

    const int B     = (E + CHUNK - 1) / CHUNK;       // edge chunks
    const int nbins = (N + 255) >> 8;                // coarse bins
    const int nM    = nbins * B;
    const int nsb   = (nM + 1023) / 1024;

    // workspace layout (16B aligned pieces)
    char* ws = (char*)d_ws;
    float* Wc = (float*)ws;                                    // 64 KB
    size_t off = 65536;
    float* bc    = (float*)(ws + off); off += 512;
    float* lbias = (float*)(ws + off); off += 1024;
    unsigned short* Wcat = (unsigned short*)(ws + off); off += 36864;
    unsigned short* W2l  = (unsigned short*)(ws + off); off += 32768;
    unsigned short* xb   = (unsigned short*)(ws + off); off += (size_t)N * D128 * 2;
    unsigned short* hfeat = (unsigned short*)(ws + off); off += (size_t)N * D128 * 2;
    float* asrc = (float*)(ws + off); off += (size_t)N * 4 * 4;
    float* adst = (float*)(ws + off); off += (size_t)N * 4 * 4;
    int* M       = (int*)(ws + off); off += (size_t)nM * 4;
    int* scanned = (int*)(ws + off); off += (size_t)nM * 4;
    int* bsum    = (int*)(ws + off); off += 1024 * 4;
    int2* binned = (int2*)(ws + off); off += (size_t)E * 8;
    int* bucket  = (int*)(ws + off); off += (size_t)E * 4;
    int* rowstart = (int*)(ws + off); off += (size_t)N * 4;
    int* rowend   = (int*)(ws + off); off += (size_t)N * 4;
    unsigned short* outbf = (unsigned short*)(ws + off); off += (size_t)N * D128 * 2;

    // 1) compose Wc + dst histogram + bf16(leaky(x))
    k_prep1<<<64 + B + XBB, 256, 0, stream>>>(x, W1, Wg, b1, ei, M, Wc, bc, xb,
                                              N, E, B, nbins);
    // 2) fragment-major weights + scan of M
    k_prep2s<<<18 + nsb, 256, 0, stream>>>(Wc, bc, atts, attd, W2, Wcat, W2l,
                                           lbias, M, scanned, bsum, nM);
    // 3) h/logits GEMM (row-major hfeat) + edge scatter into bins
    const int nbg = (N + 63) / 64;
    k_gemmA2<<<nbg + B, 256, 0, stream>>>(xb, Wcat, lbias, hfeat, asrc, adst,
                                          ei, scanned, bsum, binned,
                                          N, E, B, nbins, nM, nbg);
    // 4) bin-local CSR
    kB<<<nbins, 256, 0, stream>>>(binned, scanned, bsum, bucket,
                                  rowstart, rowend, E, B, nbins, N, nM);
    // 5) gather-style GAT aggregation (fused softmax + bias_g + leaky), depth-2
    k_gat<<<(N + 15) / 16, 256, 0, stream>>>(bucket, rowstart, rowend,
                                             asrc, adst, hfeat, bg, outbf, N);
    // 6) final GEMM
    k_final<<<nbg, 256, 0, stream>>>(outbf, W2l, b2, out, N);
}

// Round 7
// 291.882 us; speedup vs baseline: 1.9011x; 1.0978x over previous
//
#include <hip/hip_runtime.h>
#include <hip/hip_bf16.h>

#define D128 128

typedef __attribute__((ext_vector_type(8))) short bf16x8;
typedef __attribute__((ext_vector_type(4))) float f32x4;

__device__ __forceinline__ float b2f(unsigned short u) {
    union { unsigned int i; float f; } z;
    z.i = ((unsigned int)u) << 16;
    return z.f;
}

__device__ __forceinline__ unsigned short f2b(float f) {
    union { float f; unsigned int i; } z;
    z.f = f;
    unsigned int r = z.i + 0x7FFFu + ((z.i >> 16) & 1u);  // round-to-nearest-even
    return (unsigned short)(r >> 16);
}

__device__ __forceinline__ f32x4 mfma16(bf16x8 a, bf16x8 b, f32x4 c) {
    return __builtin_amdgcn_mfma_f32_16x16x32_bf16(a, b, c, 0, 0, 0);
}

#define CHUNK 8192
#define MAXBINS 512
#define BINCAP 8192

// ---------------------------------------------------------------------------
// Prep 1 (2-way block partition):
//   blocks [0,64)    : compose Wc = Wg @ W1 (fp32), bc = Wg @ b1
//   blocks [64,64+B) : per-chunk dst histogram -> M[bin*B + chunk]
// ---------------------------------------------------------------------------
__global__ __launch_bounds__(256) void k_prep1(
    const float* __restrict__ W1, const float* __restrict__ Wg,
    const float* __restrict__ b1,
    const int* __restrict__ ei, int* __restrict__ M,
    float* __restrict__ Wc, float* __restrict__ bc,
    int E, int B, int nbins)
{
    __shared__ float wgr[256];
    __shared__ int hist[MAXBINS];
    const int t = threadIdx.x;
    if (blockIdx.x < 64) {
        const int i0 = blockIdx.x * 2;
        wgr[t] = Wg[i0 * 128 + t];          // rows i0, i0+1 contiguous
        __syncthreads();
        const int half = t >> 7;
        const int j = t & 127;
        const float* wr = &wgr[half * 128];
        float acc = 0.f;
        #pragma unroll 4
        for (int k = 0; k < 128; ++k)
            acc += wr[k] * W1[k * 128 + j];
        Wc[(i0 + half) * 128 + j] = acc;
        if (j == 0) {
            float ab = 0.f;
            for (int k = 0; k < 128; ++k) ab += wr[k] * b1[k];
            bc[i0 + half] = ab;
        }
    } else {
        const int chunk = blockIdx.x - 64;
        for (int i = t; i < nbins; i += 256) hist[i] = 0;
        __syncthreads();
        const int base = chunk * CHUNK;
        const int end = min(base + CHUNK, E);
        for (int e = base + t; e < end; e += 256)
            atomicAdd(&hist[ei[E + e] >> 8], 1);
        __syncthreads();
        for (int i = t; i < nbins; i += 256)
            M[i * B + chunk] = hist[i];
    }
}

// ---------------------------------------------------------------------------
// Prep 2 + scan1 merged:
//   blocks 0..8   : Wcat fragment-major build (rows 128..143 = att-folded)
//   blocks 9..16  : W2l fragment-major build
//   block  17     : lbias
//   blocks 18..   : scan of M (1024 elems per block, 256 threads x 4)
// ---------------------------------------------------------------------------
__global__ __launch_bounds__(256) void k_prep2s(
    const float* __restrict__ Wc, const float* __restrict__ bc,
    const float* __restrict__ att_s, const float* __restrict__ att_d,
    const float* __restrict__ W2,
    unsigned short* __restrict__ Wcat, unsigned short* __restrict__ W2l,
    float* __restrict__ lbias,
    const int* __restrict__ M, int* __restrict__ scanned,
    int* __restrict__ bsum, int nM)
{
    __shared__ int lds[256];
    const int b = blockIdx.x, t = threadIdx.x;
    if (b < 9) {
        const int q = b * 256 + t;           // 0..2303
        const int ct = q >> 8, rem = q & 255;
        const int ks = rem >> 6, lane = rem & 63;
        const int ldiv = lane >> 4, lmod = lane & 15;
        const int kb = ks * 32 + ldiv * 8;
        float v[8];
        if (ct < 8) {
            const int rho = ct * 16 + lmod;
            const float4 a = *(const float4*)(Wc + rho * 128 + kb);
            const float4 bq = *(const float4*)(Wc + rho * 128 + kb + 4);
            v[0] = a.x; v[1] = a.y; v[2] = a.z; v[3] = a.w;
            v[4] = bq.x; v[5] = bq.y; v[6] = bq.z; v[7] = bq.w;
        } else {
            #pragma unroll
            for (int e = 0; e < 8; ++e) v[e] = 0.f;
            if (lmod < 8) {
                const int hh = lmod & 3;
                const float* av = lmod < 4 ? att_s : att_d;
                for (int c = 0; c < 32; ++c) {
                    const float w = av[hh * 32 + c];
                    const float* wrow = Wc + (hh * 32 + c) * 128 + kb;
                    #pragma unroll
                    for (int e = 0; e < 8; ++e) v[e] += w * wrow[e];
                }
            }
        }
        union { uint4 qq; unsigned short s[8]; } o;
        #pragma unroll
        for (int e = 0; e < 8; ++e) o.s[e] = f2b(v[e]);
        *(uint4*)(Wcat + q * 8) = o.qq;
    } else if (b < 17) {
        const int q = (b - 9) * 256 + t;     // 0..2047
        const int ct = q >> 8, rem = q & 255;
        const int ks = rem >> 6, lane = rem & 63;
        const int ldiv = lane >> 4, lmod = lane & 15;
        const int kb = ks * 32 + ldiv * 8;
        const int rho = ct * 16 + lmod;
        const float4 a = *(const float4*)(W2 + rho * 128 + kb);
        const float4 bq = *(const float4*)(W2 + rho * 128 + kb + 4);
        union { uint4 qq; unsigned short s[8]; } o;
        o.s[0] = f2b(a.x); o.s[1] = f2b(a.y); o.s[2] = f2b(a.z); o.s[3] = f2b(a.w);
        o.s[4] = f2b(bq.x); o.s[5] = f2b(bq.y); o.s[6] = f2b(bq.z); o.s[7] = f2b(bq.w);
        *(uint4*)(W2l + q * 8) = o.qq;
    } else if (b == 17) {
        if (t < 144) {
            float v = 0.f;
            if (t < 128) v = bc[t];
            else if (t < 136) {
                const int hh = (t - 128) & 3;
                const float* av = t < 132 ? att_s : att_d;
                for (int c = 0; c < 32; ++c) v += av[hh * 32 + c] * bc[hh * 32 + c];
            }
            lbias[t] = v;
        }
    } else {
        // scan block: 1024 elements, exclusive within block
        const int sid = b - 18;
        const int g0 = sid * 1024 + t * 4;
        int v0 = g0     < nM ? M[g0]     : 0;
        int v1 = g0 + 1 < nM ? M[g0 + 1] : 0;
        int v2 = g0 + 2 < nM ? M[g0 + 2] : 0;
        int v3 = g0 + 3 < nM ? M[g0 + 3] : 0;
        const int s = v0 + v1 + v2 + v3;
        lds[t] = s;
        __syncthreads();
        #pragma unroll
        for (int off = 1; off < 256; off <<= 1) {
            int tv = t >= off ? lds[t - off] : 0;
            __syncthreads();
            lds[t] += tv;
            __syncthreads();
        }
        int run = lds[t] - s;   // exclusive
        if (g0     < nM) scanned[g0]     = run;
        run += v0;
        if (g0 + 1 < nM) scanned[g0 + 1] = run;
        run += v1;
        if (g0 + 2 < nM) scanned[g0 + 2] = run;
        run += v2;
        if (g0 + 3 < nM) scanned[g0 + 3] = run;
        if (t == 255) bsum[sid] = lds[255];
    }
}

// ---------------------------------------------------------------------------
// GEMM (h + logits) merged with edge scatter (independent block ranges).
//   blocks [0, nbg)     : h = leaky(x)@Wcat^T -> hfeat + asrc/adst
//                         (A-path reads fp32 x, converts in-register — no xb)
//   blocks [nbg, nbg+B) : scatter packed (dlocal<<20|src) into bin regions
// ---------------------------------------------------------------------------
__global__ __launch_bounds__(256) void k_gemmA2(
    const float* __restrict__ x,
    const unsigned short* __restrict__ Wcat,
    const float* __restrict__ lbias,
    unsigned short* __restrict__ hfeat,
    float* __restrict__ asrc, float* __restrict__ adst,
    const int* __restrict__ ei, const int* __restrict__ scanned,
    const int* __restrict__ bsum, unsigned int* __restrict__ binned,
    int N, int E, int B, int nbins, int nM, int nbg)
{
    __shared__ __align__(16) unsigned char smem[36864];
    const int t = threadIdx.x;
    if (blockIdx.x < nbg) {
        unsigned short* sW = (unsigned short*)smem;
        const int wave = t >> 6, lane = t & 63, lmod = lane & 15, ldiv = lane >> 4;
        const int rowBase = blockIdx.x * 64;

        uint4 w[9];
        #pragma unroll
        for (int r = 0; r < 9; ++r)
            w[r] = *(const uint4*)(Wcat + r * 2048 + t * 8);

        int row = rowBase + wave * 16 + lmod;
        row = min(row, N - 1);
        bf16x8 afr[4];
        #pragma unroll
        for (int ks = 0; ks < 4; ++ks) {
            const float* px = x + (size_t)row * D128 + ks * 32 + ldiv * 8;
            float4 f0 = *(const float4*)px;
            float4 f1 = *(const float4*)(px + 4);
            float tmp[8] = { f0.x, f0.y, f0.z, f0.w, f1.x, f1.y, f1.z, f1.w };
            union { bf16x8 v; unsigned short s[8]; } o;
            #pragma unroll
            for (int jj = 0; jj < 8; ++jj) {
                float f = tmp[jj];
                f = f >= 0.f ? f : 0.01f * f;
                o.s[jj] = f2b(f);
            }
            afr[ks] = o.v;
        }

        #pragma unroll
        for (int r = 0; r < 9; ++r)
            *(uint4*)&sW[r * 2048 + t * 8] = w[r];
        __syncthreads();

        f32x4 acc[9] = {};
        #pragma unroll
        for (int ct = 0; ct < 9; ++ct) {
            #pragma unroll
            for (int ks = 0; ks < 4; ++ks) {
                bf16x8 bfr = *(const bf16x8*)&sW[(ct * 256 + ks * 64 + lane) * 8];
                acc[ct] = mfma16(afr[ks], bfr, acc[ct]);
            }
        }

        const int orow = rowBase + wave * 16 + ldiv * 4;
        #pragma unroll
        for (int ct = 0; ct < 8; ++ct) {
            const int col = ct * 16 + lmod;
            const float bias = lbias[col];
            #pragma unroll
            for (int r = 0; r < 4; ++r)
                if (orow + r < N)
                    hfeat[(size_t)(orow + r) * D128 + col] = f2b(acc[ct][r] + bias);
        }
        if (lmod < 8) {
            const float lb = lbias[128 + lmod];
            float* dst = lmod < 4 ? asrc : adst;
            const int hh = lmod & 3;
            #pragma unroll
            for (int r = 0; r < 4; ++r)
                if (orow + r < N)
                    dst[(size_t)(orow + r) * 4 + hh] = acc[8][r] + lb;
        }
    } else {
        int* cursor = (int*)smem;                      // MAXBINS ints
        int* bpre   = (int*)(smem + MAXBINS * 4);      // 1024 ints
        const int chunk = blockIdx.x - nbg;
        const int nsb = (nM + 1023) >> 10;
        for (int i = t; i < nsb; i += 256) bpre[i] = bsum[i];
        __syncthreads();
        if (t == 0) {
            int run = 0;
            for (int i = 0; i < nsb; ++i) { int tv = bpre[i]; bpre[i] = run; run += tv; }
        }
        __syncthreads();
        for (int i = t; i < nbins; i += 256) {
            const int idx = i * B + chunk;
            cursor[i] = scanned[idx] + bpre[idx >> 10];
        }
        __syncthreads();
        const int base = chunk * CHUNK;
        const int end = min(base + CHUNK, E);
        for (int e = base + t; e < end; e += 256) {
            const int s = ei[e], d = ei[E + e];
            const int pos = atomicAdd(&cursor[d >> 8], 1);   // LDS atomic (fast)
            binned[pos] = ((unsigned int)(d & 255) << 20) | (unsigned int)s;
        }
    }
}

// ---------------------------------------------------------------------------
// kB: per-bin local CSR in LDS -> bucket + rowstart/rowend. Local bsum prefix.
// binned entries are packed (dlocal<<20 | src), src < 2^20.
// ---------------------------------------------------------------------------
__global__ __launch_bounds__(256) void kB(
    const unsigned int* __restrict__ binned, const int* __restrict__ scanned,
    const int* __restrict__ bsum, int* __restrict__ bucket,
    int* __restrict__ rowstart, int* __restrict__ rowend,
    int E, int B, int nbins, int N, int nM)
{
    __shared__ unsigned int eb[BINCAP];    // 32 KB
    __shared__ int ldeg[256];
    __shared__ int lscan[256];
    __shared__ int lcur[256];
    __shared__ int bpre[1024];
    const int nsb = (nM + 1023) >> 10;
    for (int i = threadIdx.x; i < nsb; i += 256) bpre[i] = bsum[i];
    __syncthreads();
    if (threadIdx.x == 0) {
        int run = 0;
        for (int i = 0; i < nsb; ++i) { int tv = bpre[i]; bpre[i] = run; run += tv; }
    }
    __syncthreads();
    const int bin = blockIdx.x;
    const int i0 = bin * B;
    const int binstart = scanned[i0] + bpre[i0 >> 10];
    int binend;
    if (bin + 1 < nbins) {
        const int i1 = (bin + 1) * B;
        binend = scanned[i1] + bpre[i1 >> 10];
    } else {
        binend = E;
    }
    int n = binend - binstart;
    if (n > BINCAP) n = BINCAP;   // statistically impossible; safety clamp

    for (int i = threadIdx.x; i < n; i += 256) eb[i] = binned[binstart + i];
    ldeg[threadIdx.x] = 0;
    __syncthreads();
    for (int i = threadIdx.x; i < n; i += 256)
        atomicAdd(&ldeg[eb[i] >> 20], 1);
    __syncthreads();
    const int v = ldeg[threadIdx.x];
    lscan[threadIdx.x] = v;
    __syncthreads();
    #pragma unroll
    for (int off = 1; off < 256; off <<= 1) {
        int tv = threadIdx.x >= off ? lscan[threadIdx.x - off] : 0;
        __syncthreads();
        lscan[threadIdx.x] += tv;
        __syncthreads();
    }
    const int excl = lscan[threadIdx.x] - v;
    lcur[threadIdx.x] = excl;
    const int d = (bin << 8) + threadIdx.x;
    if (d < N) {
        rowstart[d] = binstart + excl;
        rowend[d]   = binstart + excl + v;
    }
    __syncthreads();
    for (int i = threadIdx.x; i < n; i += 256) {
        const unsigned int p = eb[i];
        const int lp = atomicAdd(&lcur[p >> 20], 1);  // LDS atomic
        bucket[binstart + lp] = (int)(p & 0xFFFFFu);
    }
}

// ---------------------------------------------------------------------------
// GAT aggregation, 16 lanes per dst, depth-2 (best measured). Epilogue bakes
// +bias_g and leaky(0.01) so k_final's A-operand is load-only bf16.
// ---------------------------------------------------------------------------
__global__ __launch_bounds__(256) void k_gat(
    const int* __restrict__ bucket,
    const int* __restrict__ rowstart, const int* __restrict__ rowend,
    const float* __restrict__ asrc, const float* __restrict__ adst,
    const unsigned short* __restrict__ hfeat,
    const float* __restrict__ bias_g,
    unsigned short* __restrict__ outbf, int N)
{
    const int wave = threadIdx.x >> 6;
    const int lane = threadIdx.x & 63;
    const int g    = lane >> 4;          // dst-group within wave (0..3)
    const int gl   = lane & 15;          // lane within group
    const int h    = gl >> 2;            // head 0..3
    const int d    = blockIdx.x * 16 + wave * 4 + g;

    int start = 0, end = 0;
    float a_d = 0.f;
    if (d < N) {
        start = rowstart[d];
        end   = rowend[d];
        a_d   = adst[(size_t)d * 4 + h];
    }
    const unsigned int chb = (unsigned int)(gl << 3);   // channel offset (elems)
    const unsigned short* hbase = hfeat + chb;

    float acc[8] = {0.f, 0.f, 0.f, 0.f, 0.f, 0.f, 0.f, 0.f};
    float denom = 0.f;

    int j = start;
    for (; j + 2 <= end; j += 2) {
        const int s0 = bucket[j];
        const int s1 = bucket[j + 1];
        const float as0 = asrc[((size_t)s0 << 2) + h];
        const float as1 = asrc[((size_t)s1 << 2) + h];
        const uint4 hp0 = *(const uint4*)(hbase + ((unsigned int)s0 << 7));
        const uint4 hp1 = *(const uint4*)(hbase + ((unsigned int)s1 << 7));
        float a0 = as0 + a_d; a0 = a0 >= 0.f ? a0 : 0.2f * a0;
        float a1 = as1 + a_d; a1 = a1 >= 0.f ? a1 : 0.2f * a1;
        const float w0 = __expf(a0), w1 = __expf(a1);
        denom += w0 + w1;
        acc[0] += w0 * b2f((unsigned short)(hp0.x & 0xFFFFu)) + w1 * b2f((unsigned short)(hp1.x & 0xFFFFu));
        acc[1] += w0 * b2f((unsigned short)(hp0.x >> 16))     + w1 * b2f((unsigned short)(hp1.x >> 16));
        acc[2] += w0 * b2f((unsigned short)(hp0.y & 0xFFFFu)) + w1 * b2f((unsigned short)(hp1.y & 0xFFFFu));
        acc[3] += w0 * b2f((unsigned short)(hp0.y >> 16))     + w1 * b2f((unsigned short)(hp1.y >> 16));
        acc[4] += w0 * b2f((unsigned short)(hp0.z & 0xFFFFu)) + w1 * b2f((unsigned short)(hp1.z & 0xFFFFu));
        acc[5] += w0 * b2f((unsigned short)(hp0.z >> 16))     + w1 * b2f((unsigned short)(hp1.z >> 16));
        acc[6] += w0 * b2f((unsigned short)(hp0.w & 0xFFFFu)) + w1 * b2f((unsigned short)(hp1.w & 0xFFFFu));
        acc[7] += w0 * b2f((unsigned short)(hp0.w >> 16))     + w1 * b2f((unsigned short)(hp1.w >> 16));
    }
    if (j < end) {
        const int s0 = bucket[j];
        const float as0 = asrc[((size_t)s0 << 2) + h];
        const uint4 hp0 = *(const uint4*)(hbase + ((unsigned int)s0 << 7));
        float a0 = as0 + a_d; a0 = a0 >= 0.f ? a0 : 0.2f * a0;
        const float w0 = __expf(a0);
        denom += w0;
        acc[0] += w0 * b2f((unsigned short)(hp0.x & 0xFFFFu));
        acc[1] += w0 * b2f((unsigned short)(hp0.x >> 16));
        acc[2] += w0 * b2f((unsigned short)(hp0.y & 0xFFFFu));
        acc[3] += w0 * b2f((unsigned short)(hp0.y >> 16));
        acc[4] += w0 * b2f((unsigned short)(hp0.z & 0xFFFFu));
        acc[5] += w0 * b2f((unsigned short)(hp0.z >> 16));
        acc[6] += w0 * b2f((unsigned short)(hp0.w & 0xFFFFu));
        acc[7] += w0 * b2f((unsigned short)(hp0.w >> 16));
    }

    if (d < N) {
        const float inv = 1.f / (denom + 1e-16f);
        const float4 bg0 = *(const float4*)(bias_g + chb);
        const float4 bg1 = *(const float4*)(bias_g + chb + 4);
        const float bg[8] = { bg0.x, bg0.y, bg0.z, bg0.w, bg1.x, bg1.y, bg1.z, bg1.w };
        unsigned short s[8];
        #pragma unroll
        for (int k2 = 0; k2 < 8; ++k2) {
            float v = acc[k2] * inv + bg[k2];
            v = v >= 0.f ? v : 0.01f * v;
            s[k2] = f2b(v);
        }
        uint4 o;
        o.x = ((unsigned int)s[1] << 16) | s[0];
        o.y = ((unsigned int)s[3] << 16) | s[2];
        o.z = ((unsigned int)s[5] << 16) | s[4];
        o.w = ((unsigned int)s[7] << 16) | s[6];
        *(uint4*)(outbf + (((unsigned int)d << 7) + chb)) = o;
    }
}

// ---------------------------------------------------------------------------
// Final GEMM: out = outbf @ W2^T + b2  (A already has bias+leaky baked in)
// ---------------------------------------------------------------------------
__global__ __launch_bounds__(256) void k_final(
    const unsigned short* __restrict__ gatbf,
    const unsigned short* __restrict__ W2l,
    const float* __restrict__ b2,
    float* __restrict__ out, int N)
{
    __shared__ __align__(16) unsigned short sW[16384];   // 32768 B
    const int t = threadIdx.x;
    const int wave = t >> 6, lane = t & 63, lmod = lane & 15, ldiv = lane >> 4;
    const int rowBase = blockIdx.x * 64;

    uint4 w[8];
    #pragma unroll
    for (int r = 0; r < 8; ++r)
        w[r] = *(const uint4*)(W2l + r * 2048 + t * 8);

    int row = rowBase + wave * 16 + lmod;
    row = min(row, N - 1);
    bf16x8 afr[4];
    #pragma unroll
    for (int ks = 0; ks < 4; ++ks)
        afr[ks] = *(const bf16x8*)(gatbf + (size_t)row * D128 + ks * 32 + ldiv * 8);

    #pragma unroll
    for (int r = 0; r < 8; ++r)
        *(uint4*)&sW[r * 2048 + t * 8] = w[r];
    __syncthreads();

    f32x4 acc[8] = {};
    #pragma unroll
    for (int ct = 0; ct < 8; ++ct) {
        #pragma unroll
        for (int ks = 0; ks < 4; ++ks) {
            bf16x8 bfr = *(const bf16x8*)&sW[(ct * 256 + ks * 64 + lane) * 8];
            acc[ct] = mfma16(afr[ks], bfr, acc[ct]);
        }
    }

    const int orow = rowBase + wave * 16 + ldiv * 4;
    #pragma unroll
    for (int ct = 0; ct < 8; ++ct) {
        const int col = ct * 16 + lmod;
        const float bb = b2[col];
        #pragma unroll
        for (int r = 0; r < 4; ++r)
            if (orow + r < N)
                out[(size_t)(orow + r) * D128 + col] = acc[ct][r] + bb;
    }
}

// ---------------------------------------------------------------------------
extern "C" void kernel_launch(void* const* d_in, const int* in_sizes, int n_in,
                              void* d_out, int out_size, void* d_ws, size_t ws_size,
                              hipStream_t stream)
{
    const float* x    = (const float*)d_in[0];
    const int*   ei   = (const int*)d_in[1];
    // d_in[2] edge_type: unused by forward
    const float* W1   = (const float*)d_in[3];
    const float* b1   = (const float*)d_in[4];
    const float* Wg   = (const float*)d_in[5];
    const float* atts = (const float*)d_in[6];
    const float* attd = (const float*)d_in[7];
    const float* bg   = (const float*)d_in[8];
    const float* W2   = (const float*)d_in[9];
    const float* b2   = (const float*)d_in[10];
    float* out = (float*)d_out;

    const int N = in_sizes[0] / D128;
    const int E = in_sizes[1] / 2;

    const int B     = (E + CHUNK - 1) / CHUNK;       // edge chunks
    const int nbins = (N + 255) >> 8;                // coarse bins
    const int nM    = nbins * B;
    const int nsb   = (nM + 1023) / 1024;

    // workspace layout (16B aligned pieces)
    char* ws = (char*)d_ws;
    float* Wc = (float*)ws;                                    // 64 KB
    size_t off = 65536;
    float* bc    = (float*)(ws + off); off += 512;
    float* lbias = (float*)(ws + off); off += 1024;
    unsigned short* Wcat = (unsigned short*)(ws + off); off += 36864;
    unsigned short* W2l  = (unsigned short*)(ws + off); off += 32768;
    unsigned short* hfeat = (unsigned short*)(ws + off); off += (size_t)N * D128 * 2;
    float* asrc = (float*)(ws + off); off += (size_t)N * 4 * 4;
    float* adst = (float*)(ws + off); off += (size_t)N * 4 * 4;
    int* M       = (int*)(ws + off); off += (size_t)nM * 4;
    int* scanned = (int*)(ws + off); off += (size_t)nM * 4;
    int* bsum    = (int*)(ws + off); off += 1024 * 4;
    unsigned int* binned = (unsigned int*)(ws + off); off += (size_t)E * 4;
    int* bucket  = (int*)(ws + off); off += (size_t)E * 4;
    int* rowstart = (int*)(ws + off); off += (size_t)N * 4;
    int* rowend   = (int*)(ws + off); off += (size_t)N * 4;
    unsigned short* outbf = (unsigned short*)(ws + off); off += (size_t)N * D128 * 2;

    // 1) compose Wc + dst histogram
    k_prep1<<<64 + B, 256, 0, stream>>>(W1, Wg, b1, ei, M, Wc, bc, E, B, nbins);
    // 2) fragment-major weights + scan of M
    k_prep2s<<<18 + nsb, 256, 0, stream>>>(Wc, bc, atts, attd, W2, Wcat, W2l,
                                           lbias, M, scanned, bsum, nM);
    // 3) h/logits GEMM (fp32 x, in-register leaky+cvt) + edge scatter
    const int nbg = (N + 63) / 64;
    k_gemmA2<<<nbg + B, 256, 0, stream>>>(x, Wcat, lbias, hfeat, asrc, adst,
                                          ei, scanned, bsum, binned,
                                          N, E, B, nbins, nM, nbg);
    // 4) bin-local CSR
    kB<<<nbins, 256, 0, stream>>>(binned, scanned, bsum, bucket,
                                  rowstart, rowend, E, B, nbins, N, nM);
    // 5) gather-style GAT aggregation (fused softmax + bias_g + leaky), depth-2
    k_gat<<<(N + 15) / 16, 256, 0, stream>>>(bucket, rowstart, rowend,
                                             asrc, adst, hfeat, bg, outbf, N);
    // 6) final GEMM
    k_final<<<nbg, 256, 0, stream>>>(outbf, W2l, b2, out, N);
}

// Round 8
// 275.258 us; speedup vs baseline: 2.0159x; 1.0604x over previous
//
#include <hip/hip_runtime.h>
#include <hip/hip_bf16.h>

#define D128 128

typedef __attribute__((ext_vector_type(8))) short bf16x8;
typedef __attribute__((ext_vector_type(4))) float f32x4;

__device__ __forceinline__ float b2f(unsigned short u) {
    union { unsigned int i; float f; } z;
    z.i = ((unsigned int)u) << 16;
    return z.f;
}

__device__ __forceinline__ unsigned short f2b(float f) {
    union { float f; unsigned int i; } z;
    z.f = f;
    unsigned int r = z.i + 0x7FFFu + ((z.i >> 16) & 1u);  // round-to-nearest-even
    return (unsigned short)(r >> 16);
}

__device__ __forceinline__ f32x4 mfma16(bf16x8 a, bf16x8 b, f32x4 c) {
    return __builtin_amdgcn_mfma_f32_16x16x32_bf16(a, b, c, 0, 0, 0);
}

#define CHUNK 8192
#define MAXBINS 512
#define BINCAP 8192
#define NGB 768    // persistent GEMM blocks (h-GEMM)
#define NFB 768    // persistent blocks (final GEMM)

// ---------------------------------------------------------------------------
// Prep 1 (2-way block partition):
//   blocks [0,64)    : compose Wc = Wg @ W1 (fp32), bc = Wg @ b1
//   blocks [64,64+B) : per-chunk dst histogram -> M[bin*B + chunk]
// ---------------------------------------------------------------------------
__global__ __launch_bounds__(256) void k_prep1(
    const float* __restrict__ W1, const float* __restrict__ Wg,
    const float* __restrict__ b1,
    const int* __restrict__ ei, int* __restrict__ M,
    float* __restrict__ Wc, float* __restrict__ bc,
    int E, int B, int nbins)
{
    __shared__ float wgr[256];
    __shared__ int hist[MAXBINS];
    const int t = threadIdx.x;
    if (blockIdx.x < 64) {
        const int i0 = blockIdx.x * 2;
        wgr[t] = Wg[i0 * 128 + t];          // rows i0, i0+1 contiguous
        __syncthreads();
        const int half = t >> 7;
        const int j = t & 127;
        const float* wr = &wgr[half * 128];
        float acc = 0.f;
        #pragma unroll 4
        for (int k = 0; k < 128; ++k)
            acc += wr[k] * W1[k * 128 + j];
        Wc[(i0 + half) * 128 + j] = acc;
        if (j == 0) {
            float ab = 0.f;
            for (int k = 0; k < 128; ++k) ab += wr[k] * b1[k];
            bc[i0 + half] = ab;
        }
    } else {
        const int chunk = blockIdx.x - 64;
        for (int i = t; i < nbins; i += 256) hist[i] = 0;
        __syncthreads();
        const int base = chunk * CHUNK;
        const int end = min(base + CHUNK, E);
        for (int e = base + t; e < end; e += 256)
            atomicAdd(&hist[ei[E + e] >> 8], 1);
        __syncthreads();
        for (int i = t; i < nbins; i += 256)
            M[i * B + chunk] = hist[i];
    }
}

// ---------------------------------------------------------------------------
// Prep 2 + scan1 merged (unchanged from round 7).
// ---------------------------------------------------------------------------
__global__ __launch_bounds__(256) void k_prep2s(
    const float* __restrict__ Wc, const float* __restrict__ bc,
    const float* __restrict__ att_s, const float* __restrict__ att_d,
    const float* __restrict__ W2,
    unsigned short* __restrict__ Wcat, unsigned short* __restrict__ W2l,
    float* __restrict__ lbias,
    const int* __restrict__ M, int* __restrict__ scanned,
    int* __restrict__ bsum, int nM)
{
    __shared__ int lds[256];
    const int b = blockIdx.x, t = threadIdx.x;
    if (b < 9) {
        const int q = b * 256 + t;           // 0..2303
        const int ct = q >> 8, rem = q & 255;
        const int ks = rem >> 6, lane = rem & 63;
        const int ldiv = lane >> 4, lmod = lane & 15;
        const int kb = ks * 32 + ldiv * 8;
        float v[8];
        if (ct < 8) {
            const int rho = ct * 16 + lmod;
            const float4 a = *(const float4*)(Wc + rho * 128 + kb);
            const float4 bq = *(const float4*)(Wc + rho * 128 + kb + 4);
            v[0] = a.x; v[1] = a.y; v[2] = a.z; v[3] = a.w;
            v[4] = bq.x; v[5] = bq.y; v[6] = bq.z; v[7] = bq.w;
        } else {
            #pragma unroll
            for (int e = 0; e < 8; ++e) v[e] = 0.f;
            if (lmod < 8) {
                const int hh = lmod & 3;
                const float* av = lmod < 4 ? att_s : att_d;
                for (int c = 0; c < 32; ++c) {
                    const float w = av[hh * 32 + c];
                    const float* wrow = Wc + (hh * 32 + c) * 128 + kb;
                    #pragma unroll
                    for (int e = 0; e < 8; ++e) v[e] += w * wrow[e];
                }
            }
        }
        union { uint4 qq; unsigned short s[8]; } o;
        #pragma unroll
        for (int e = 0; e < 8; ++e) o.s[e] = f2b(v[e]);
        *(uint4*)(Wcat + q * 8) = o.qq;
    } else if (b < 17) {
        const int q = (b - 9) * 256 + t;     // 0..2047
        const int ct = q >> 8, rem = q & 255;
        const int ks = rem >> 6, lane = rem & 63;
        const int ldiv = lane >> 4, lmod = lane & 15;
        const int kb = ks * 32 + ldiv * 8;
        const int rho = ct * 16 + lmod;
        const float4 a = *(const float4*)(W2 + rho * 128 + kb);
        const float4 bq = *(const float4*)(W2 + rho * 128 + kb + 4);
        union { uint4 qq; unsigned short s[8]; } o;
        o.s[0] = f2b(a.x); o.s[1] = f2b(a.y); o.s[2] = f2b(a.z); o.s[3] = f2b(a.w);
        o.s[4] = f2b(bq.x); o.s[5] = f2b(bq.y); o.s[6] = f2b(bq.z); o.s[7] = f2b(bq.w);
        *(uint4*)(W2l + q * 8) = o.qq;
    } else if (b == 17) {
        if (t < 144) {
            float v = 0.f;
            if (t < 128) v = bc[t];
            else if (t < 136) {
                const int hh = (t - 128) & 3;
                const float* av = t < 132 ? att_s : att_d;
                for (int c = 0; c < 32; ++c) v += av[hh * 32 + c] * bc[hh * 32 + c];
            }
            lbias[t] = v;
        }
    } else {
        // scan block: 1024 elements, exclusive within block
        const int sid = b - 18;
        const int g0 = sid * 1024 + t * 4;
        int v0 = g0     < nM ? M[g0]     : 0;
        int v1 = g0 + 1 < nM ? M[g0 + 1] : 0;
        int v2 = g0 + 2 < nM ? M[g0 + 2] : 0;
        int v3 = g0 + 3 < nM ? M[g0 + 3] : 0;
        const int s = v0 + v1 + v2 + v3;
        lds[t] = s;
        __syncthreads();
        #pragma unroll
        for (int off = 1; off < 256; off <<= 1) {
            int tv = t >= off ? lds[t - off] : 0;
            __syncthreads();
            lds[t] += tv;
            __syncthreads();
        }
        int run = lds[t] - s;   // exclusive
        if (g0     < nM) scanned[g0]     = run;
        run += v0;
        if (g0 + 1 < nM) scanned[g0 + 1] = run;
        run += v1;
        if (g0 + 2 < nM) scanned[g0 + 2] = run;
        run += v2;
        if (g0 + 3 < nM) scanned[g0 + 3] = run;
        if (t == 255) bsum[sid] = lds[255];
    }
}

// ---------------------------------------------------------------------------
// PERSISTENT h-GEMM + edge scatter.
//   blocks [0, B)      : scatter packed (dlocal<<20|src) into bin regions
//   blocks [B, B+NGB)  : load Wcat->LDS once, then grid-stride over 64-row
//                        tiles: h = leaky(x)@Wcat^T -> hfeat + asrc/adst
// ---------------------------------------------------------------------------
__global__ __launch_bounds__(256) void k_gemmA2(
    const float* __restrict__ x,
    const unsigned short* __restrict__ Wcat,
    const float* __restrict__ lbias,
    unsigned short* __restrict__ hfeat,
    float* __restrict__ asrc, float* __restrict__ adst,
    const int* __restrict__ ei, const int* __restrict__ scanned,
    const int* __restrict__ bsum, unsigned int* __restrict__ binned,
    int N, int E, int B, int nbins, int nM, int ntiles)
{
    __shared__ __align__(16) unsigned char smem[36864];
    const int t = threadIdx.x;
    if (blockIdx.x >= B) {
        unsigned short* sW = (unsigned short*)smem;
        const int wave = t >> 6, lane = t & 63, lmod = lane & 15, ldiv = lane >> 4;

        // load all 144 B-fragment rows once
        #pragma unroll
        for (int r = 0; r < 9; ++r)
            *(uint4*)&sW[r * 2048 + t * 8] = *(const uint4*)(Wcat + r * 2048 + t * 8);
        __syncthreads();

        for (int tile = blockIdx.x - B; tile < ntiles; tile += NGB) {
            const int rowBase = tile * 64;
            int row = rowBase + wave * 16 + lmod;
            row = min(row, N - 1);
            bf16x8 afr[4];
            #pragma unroll
            for (int ks = 0; ks < 4; ++ks) {
                const float* px = x + (size_t)row * D128 + ks * 32 + ldiv * 8;
                float4 f0 = *(const float4*)px;
                float4 f1 = *(const float4*)(px + 4);
                float tmp[8] = { f0.x, f0.y, f0.z, f0.w, f1.x, f1.y, f1.z, f1.w };
                union { bf16x8 v; unsigned short s[8]; } o;
                #pragma unroll
                for (int jj = 0; jj < 8; ++jj) {
                    float f = tmp[jj];
                    f = f >= 0.f ? f : 0.01f * f;
                    o.s[jj] = f2b(f);
                }
                afr[ks] = o.v;
            }

            f32x4 acc[9] = {};
            #pragma unroll
            for (int ct = 0; ct < 9; ++ct) {
                #pragma unroll
                for (int ks = 0; ks < 4; ++ks) {
                    bf16x8 bfr = *(const bf16x8*)&sW[(ct * 256 + ks * 64 + lane) * 8];
                    acc[ct] = mfma16(afr[ks], bfr, acc[ct]);
                }
            }

            const int orow = rowBase + wave * 16 + ldiv * 4;
            #pragma unroll
            for (int ct = 0; ct < 8; ++ct) {
                const int col = ct * 16 + lmod;
                const float bias = lbias[col];
                #pragma unroll
                for (int r = 0; r < 4; ++r)
                    if (orow + r < N)
                        hfeat[(size_t)(orow + r) * D128 + col] = f2b(acc[ct][r] + bias);
            }
            if (lmod < 8) {
                const float lb = lbias[128 + lmod];
                float* dst = lmod < 4 ? asrc : adst;
                const int hh = lmod & 3;
                #pragma unroll
                for (int r = 0; r < 4; ++r)
                    if (orow + r < N)
                        dst[(size_t)(orow + r) * 4 + hh] = acc[8][r] + lb;
            }
        }
    } else {
        int* cursor = (int*)smem;                      // MAXBINS ints
        int* bpre   = (int*)(smem + MAXBINS * 4);      // 1024 ints
        const int chunk = blockIdx.x;
        const int nsb = (nM + 1023) >> 10;
        for (int i = t; i < nsb; i += 256) bpre[i] = bsum[i];
        __syncthreads();
        if (t == 0) {
            int run = 0;
            for (int i = 0; i < nsb; ++i) { int tv = bpre[i]; bpre[i] = run; run += tv; }
        }
        __syncthreads();
        for (int i = t; i < nbins; i += 256) {
            const int idx = i * B + chunk;
            cursor[i] = scanned[idx] + bpre[idx >> 10];
        }
        __syncthreads();
        const int base = chunk * CHUNK;
        const int end = min(base + CHUNK, E);
        for (int e = base + t; e < end; e += 256) {
            const int s = ei[e], d = ei[E + e];
            const int pos = atomicAdd(&cursor[d >> 8], 1);   // LDS atomic (fast)
            binned[pos] = ((unsigned int)(d & 255) << 20) | (unsigned int)s;
        }
    }
}

// ---------------------------------------------------------------------------
// kB: per-bin local CSR in LDS -> bucket + rowstart/rowend (unchanged).
// ---------------------------------------------------------------------------
__global__ __launch_bounds__(256) void kB(
    const unsigned int* __restrict__ binned, const int* __restrict__ scanned,
    const int* __restrict__ bsum, int* __restrict__ bucket,
    int* __restrict__ rowstart, int* __restrict__ rowend,
    int E, int B, int nbins, int N, int nM)
{
    __shared__ unsigned int eb[BINCAP];    // 32 KB
    __shared__ int ldeg[256];
    __shared__ int lscan[256];
    __shared__ int lcur[256];
    __shared__ int bpre[1024];
    const int nsb = (nM + 1023) >> 10;
    for (int i = threadIdx.x; i < nsb; i += 256) bpre[i] = bsum[i];
    __syncthreads();
    if (threadIdx.x == 0) {
        int run = 0;
        for (int i = 0; i < nsb; ++i) { int tv = bpre[i]; bpre[i] = run; run += tv; }
    }
    __syncthreads();
    const int bin = blockIdx.x;
    const int i0 = bin * B;
    const int binstart = scanned[i0] + bpre[i0 >> 10];
    int binend;
    if (bin + 1 < nbins) {
        const int i1 = (bin + 1) * B;
        binend = scanned[i1] + bpre[i1 >> 10];
    } else {
        binend = E;
    }
    int n = binend - binstart;
    if (n > BINCAP) n = BINCAP;   // statistically impossible; safety clamp

    for (int i = threadIdx.x; i < n; i += 256) eb[i] = binned[binstart + i];
    ldeg[threadIdx.x] = 0;
    __syncthreads();
    for (int i = threadIdx.x; i < n; i += 256)
        atomicAdd(&ldeg[eb[i] >> 20], 1);
    __syncthreads();
    const int v = ldeg[threadIdx.x];
    lscan[threadIdx.x] = v;
    __syncthreads();
    #pragma unroll
    for (int off = 1; off < 256; off <<= 1) {
        int tv = threadIdx.x >= off ? lscan[threadIdx.x - off] : 0;
        __syncthreads();
        lscan[threadIdx.x] += tv;
        __syncthreads();
    }
    const int excl = lscan[threadIdx.x] - v;
    lcur[threadIdx.x] = excl;
    const int d = (bin << 8) + threadIdx.x;
    if (d < N) {
        rowstart[d] = binstart + excl;
        rowend[d]   = binstart + excl + v;
    }
    __syncthreads();
    for (int i = threadIdx.x; i < n; i += 256) {
        const unsigned int p = eb[i];
        const int lp = atomicAdd(&lcur[p >> 20], 1);  // LDS atomic
        bucket[binstart + lp] = (int)(p & 0xFFFFFu);
    }
}

// ---------------------------------------------------------------------------
// GAT aggregation, 16 lanes per dst, depth-2 (unchanged, best measured).
// ---------------------------------------------------------------------------
__global__ __launch_bounds__(256) void k_gat(
    const int* __restrict__ bucket,
    const int* __restrict__ rowstart, const int* __restrict__ rowend,
    const float* __restrict__ asrc, const float* __restrict__ adst,
    const unsigned short* __restrict__ hfeat,
    const float* __restrict__ bias_g,
    unsigned short* __restrict__ outbf, int N)
{
    const int wave = threadIdx.x >> 6;
    const int lane = threadIdx.x & 63;
    const int g    = lane >> 4;          // dst-group within wave (0..3)
    const int gl   = lane & 15;          // lane within group
    const int h    = gl >> 2;            // head 0..3
    const int d    = blockIdx.x * 16 + wave * 4 + g;

    int start = 0, end = 0;
    float a_d = 0.f;
    if (d < N) {
        start = rowstart[d];
        end   = rowend[d];
        a_d   = adst[(size_t)d * 4 + h];
    }
    const unsigned int chb = (unsigned int)(gl << 3);   // channel offset (elems)
    const unsigned short* hbase = hfeat + chb;

    float acc[8] = {0.f, 0.f, 0.f, 0.f, 0.f, 0.f, 0.f, 0.f};
    float denom = 0.f;

    int j = start;
    for (; j + 2 <= end; j += 2) {
        const int s0 = bucket[j];
        const int s1 = bucket[j + 1];
        const float as0 = asrc[((size_t)s0 << 2) + h];
        const float as1 = asrc[((size_t)s1 << 2) + h];
        const uint4 hp0 = *(const uint4*)(hbase + ((unsigned int)s0 << 7));
        const uint4 hp1 = *(const uint4*)(hbase + ((unsigned int)s1 << 7));
        float a0 = as0 + a_d; a0 = a0 >= 0.f ? a0 : 0.2f * a0;
        float a1 = as1 + a_d; a1 = a1 >= 0.f ? a1 : 0.2f * a1;
        const float w0 = __expf(a0), w1 = __expf(a1);
        denom += w0 + w1;
        acc[0] += w0 * b2f((unsigned short)(hp0.x & 0xFFFFu)) + w1 * b2f((unsigned short)(hp1.x & 0xFFFFu));
        acc[1] += w0 * b2f((unsigned short)(hp0.x >> 16))     + w1 * b2f((unsigned short)(hp1.x >> 16));
        acc[2] += w0 * b2f((unsigned short)(hp0.y & 0xFFFFu)) + w1 * b2f((unsigned short)(hp1.y & 0xFFFFu));
        acc[3] += w0 * b2f((unsigned short)(hp0.y >> 16))     + w1 * b2f((unsigned short)(hp1.y >> 16));
        acc[4] += w0 * b2f((unsigned short)(hp0.z & 0xFFFFu)) + w1 * b2f((unsigned short)(hp1.z & 0xFFFFu));
        acc[5] += w0 * b2f((unsigned short)(hp0.z >> 16))     + w1 * b2f((unsigned short)(hp1.z >> 16));
        acc[6] += w0 * b2f((unsigned short)(hp0.w & 0xFFFFu)) + w1 * b2f((unsigned short)(hp1.w & 0xFFFFu));
        acc[7] += w0 * b2f((unsigned short)(hp0.w >> 16))     + w1 * b2f((unsigned short)(hp1.w >> 16));
    }
    if (j < end) {
        const int s0 = bucket[j];
        const float as0 = asrc[((size_t)s0 << 2) + h];
        const uint4 hp0 = *(const uint4*)(hbase + ((unsigned int)s0 << 7));
        float a0 = as0 + a_d; a0 = a0 >= 0.f ? a0 : 0.2f * a0;
        const float w0 = __expf(a0);
        denom += w0;
        acc[0] += w0 * b2f((unsigned short)(hp0.x & 0xFFFFu));
        acc[1] += w0 * b2f((unsigned short)(hp0.x >> 16));
        acc[2] += w0 * b2f((unsigned short)(hp0.y & 0xFFFFu));
        acc[3] += w0 * b2f((unsigned short)(hp0.y >> 16));
        acc[4] += w0 * b2f((unsigned short)(hp0.z & 0xFFFFu));
        acc[5] += w0 * b2f((unsigned short)(hp0.z >> 16));
        acc[6] += w0 * b2f((unsigned short)(hp0.w & 0xFFFFu));
        acc[7] += w0 * b2f((unsigned short)(hp0.w >> 16));
    }

    if (d < N) {
        const float inv = 1.f / (denom + 1e-16f);
        const float4 bg0 = *(const float4*)(bias_g + chb);
        const float4 bg1 = *(const float4*)(bias_g + chb + 4);
        const float bg[8] = { bg0.x, bg0.y, bg0.z, bg0.w, bg1.x, bg1.y, bg1.z, bg1.w };
        unsigned short s[8];
        #pragma unroll
        for (int k2 = 0; k2 < 8; ++k2) {
            float v = acc[k2] * inv + bg[k2];
            v = v >= 0.f ? v : 0.01f * v;
            s[k2] = f2b(v);
        }
        uint4 o;
        o.x = ((unsigned int)s[1] << 16) | s[0];
        o.y = ((unsigned int)s[3] << 16) | s[2];
        o.z = ((unsigned int)s[5] << 16) | s[4];
        o.w = ((unsigned int)s[7] << 16) | s[6];
        *(uint4*)(outbf + (((unsigned int)d << 7) + chb)) = o;
    }
}

// ---------------------------------------------------------------------------
// PERSISTENT final GEMM: load W2l->LDS once, grid-stride over 64-row tiles.
// ---------------------------------------------------------------------------
__global__ __launch_bounds__(256) void k_final(
    const unsigned short* __restrict__ gatbf,
    const unsigned short* __restrict__ W2l,
    const float* __restrict__ b2,
    float* __restrict__ out, int N, int ntiles)
{
    __shared__ __align__(16) unsigned short sW[16384];   // 32768 B
    const int t = threadIdx.x;
    const int wave = t >> 6, lane = t & 63, lmod = lane & 15, ldiv = lane >> 4;

    #pragma unroll
    for (int r = 0; r < 8; ++r)
        *(uint4*)&sW[r * 2048 + t * 8] = *(const uint4*)(W2l + r * 2048 + t * 8);
    __syncthreads();

    for (int tile = blockIdx.x; tile < ntiles; tile += NFB) {
        const int rowBase = tile * 64;
        int row = rowBase + wave * 16 + lmod;
        row = min(row, N - 1);
        bf16x8 afr[4];
        #pragma unroll
        for (int ks = 0; ks < 4; ++ks)
            afr[ks] = *(const bf16x8*)(gatbf + (size_t)row * D128 + ks * 32 + ldiv * 8);

        f32x4 acc[8] = {};
        #pragma unroll
        for (int ct = 0; ct < 8; ++ct) {
            #pragma unroll
            for (int ks = 0; ks < 4; ++ks) {
                bf16x8 bfr = *(const bf16x8*)&sW[(ct * 256 + ks * 64 + lane) * 8];
                acc[ct] = mfma16(afr[ks], bfr, acc[ct]);
            }
        }

        const int orow = rowBase + wave * 16 + ldiv * 4;
        #pragma unroll
        for (int ct = 0; ct < 8; ++ct) {
            const int col = ct * 16 + lmod;
            const float bb = b2[col];
            #pragma unroll
            for (int r = 0; r < 4; ++r)
                if (orow + r < N)
                    out[(size_t)(orow + r) * D128 + col] = acc[ct][r] + bb;
        }
    }
}

// ---------------------------------------------------------------------------
extern "C" void kernel_launch(void* const* d_in, const int* in_sizes, int n_in,
                              void* d_out, int out_size, void* d_ws, size_t ws_size,
                              hipStream_t stream)
{
    const float* x    = (const float*)d_in[0];
    const int*   ei   = (const int*)d_in[1];
    // d_in[2] edge_type: unused by forward
    const float* W1   = (const float*)d_in[3];
    const float* b1   = (const float*)d_in[4];
    const float* Wg   = (const float*)d_in[5];
    const float* atts = (const float*)d_in[6];
    const float* attd = (const float*)d_in[7];
    const float* bg   = (const float*)d_in[8];
    const float* W2   = (const float*)d_in[9];
    const float* b2   = (const float*)d_in[10];
    float* out = (float*)d_out;

    const int N = in_sizes[0] / D128;
    const int E = in_sizes[1] / 2;

    const int B     = (E + CHUNK - 1) / CHUNK;       // edge chunks
    const int nbins = (N + 255) >> 8;                // coarse bins
    const int nM    = nbins * B;
    const int nsb   = (nM + 1023) / 1024;
    const int ntiles = (N + 63) / 64;

    // workspace layout (16B aligned pieces)
    char* ws = (char*)d_ws;
    float* Wc = (float*)ws;                                    // 64 KB
    size_t off = 65536;
    float* bc    = (float*)(ws + off); off += 512;
    float* lbias = (float*)(ws + off); off += 1024;
    unsigned short* Wcat = (unsigned short*)(ws + off); off += 36864;
    unsigned short* W2l  = (unsigned short*)(ws + off); off += 32768;
    unsigned short* hfeat = (unsigned short*)(ws + off); off += (size_t)N * D128 * 2;
    float* asrc = (float*)(ws + off); off += (size_t)N * 4 * 4;
    float* adst = (float*)(ws + off); off += (size_t)N * 4 * 4;
    int* M       = (int*)(ws + off); off += (size_t)nM * 4;
    int* scanned = (int*)(ws + off); off += (size_t)nM * 4;
    int* bsum    = (int*)(ws + off); off += 1024 * 4;
    unsigned int* binned = (unsigned int*)(ws + off); off += (size_t)E * 4;
    int* bucket  = (int*)(ws + off); off += (size_t)E * 4;
    int* rowstart = (int*)(ws + off); off += (size_t)N * 4;
    int* rowend   = (int*)(ws + off); off += (size_t)N * 4;
    unsigned short* outbf = (unsigned short*)(ws + off); off += (size_t)N * D128 * 2;

    // 1) compose Wc + dst histogram
    k_prep1<<<64 + B, 256, 0, stream>>>(W1, Wg, b1, ei, M, Wc, bc, E, B, nbins);
    // 2) fragment-major weights + scan of M
    k_prep2s<<<18 + nsb, 256, 0, stream>>>(Wc, bc, atts, attd, W2, Wcat, W2l,
                                           lbias, M, scanned, bsum, nM);
    // 3) persistent h/logits GEMM + edge scatter
    k_gemmA2<<<B + NGB, 256, 0, stream>>>(x, Wcat, lbias, hfeat, asrc, adst,
                                          ei, scanned, bsum, binned,
                                          N, E, B, nbins, nM, ntiles);
    // 4) bin-local CSR
    kB<<<nbins, 256, 0, stream>>>(binned, scanned, bsum, bucket,
                                  rowstart, rowend, E, B, nbins, N, nM);
    // 5) gather-style GAT aggregation (fused softmax + bias_g + leaky), depth-2
    k_gat<<<(N + 15) / 16, 256, 0, stream>>>(bucket, rowstart, rowend,
                                             asrc, adst, hfeat, bg, outbf, N);
    // 6) persistent final GEMM
    k_final<<<NFB, 256, 0, stream>>>(outbf, W2l, b2, out, N, ntiles);
}